// Round 5
// baseline (586.291 us; speedup 1.0000x reference)
//
#include <hip/hip_runtime.h>
#include <hip/hip_bf16.h>
#include <math.h>

// Problem constants
#define DDIM 1024
#define NH   16
#define LTOK 512
#define NBATCH 16

typedef unsigned short u16;
typedef unsigned short u16x8 __attribute__((ext_vector_type(8)));
typedef unsigned short u16x4 __attribute__((ext_vector_type(4)));
typedef __bf16 bf16x8 __attribute__((ext_vector_type(8)));
typedef float f32x4 __attribute__((ext_vector_type(4)));

typedef __attribute__((address_space(1))) void as1_void;
typedef __attribute__((address_space(3))) void as3_void;

__device__ __forceinline__ void llds16(const u16* g, u16* l) {
    // async 16B global->LDS DMA; LDS dest = wave-uniform base + lane*16B
    __builtin_amdgcn_global_load_lds((as1_void*)g, (as3_void*)l, 16, 0, 0);
}

__device__ __forceinline__ float bf2f(u16 u) {
    unsigned v = ((unsigned)u) << 16;
    float f; __builtin_memcpy(&f, &v, 4); return f;
}
__device__ __forceinline__ u16 f2bf(float f) {
    unsigned u; __builtin_memcpy(&u, &f, 4);
    u += 0x7fffu + ((u >> 16) & 1u);   // RNE
    return (u16)(u >> 16);
}

// ---------------------------------------------------------------------------
// Generic MFMA GEMM:  C = act(scale*(A@BT^T)+bias).  M,N,K multiples of 128/
// 128/32 (all call sites comply -- no bounds checks).
// MODE 0: single-buffer, 2 barriers/K-step (16KB LDS) -- large grids (>=6/CU)
//         where cross-block overlap hides latency and occupancy is king.
// MODE 1: 2-buffer double-buffer, __syncthreads (32KB) -- mid grids (4/CU).
// MODE 2: 3-buffer, 2-deep prefetch, counted s_waitcnt vmcnt(4) + raw
//         s_barrier (48KB) -- starved grids (1-2 blocks/CU).  The tile being
//         read was staged ~2 compute phases ago; the freshly-issued DMA stays
//         in flight across the barrier (T4: never vmcnt(0) mid-loop).
// Epilogue computes C^T fragments via mfma operand swap so each lane holds 4
// consecutive columns -> vectorized u16x4/f32x4 stores (less RMW).
// XCD swizzle (T1) when tilesM%8==0.
// ---------------------------------------------------------------------------
template<int MODE>
__global__ __launch_bounds__(256) void gemm_bt_kernel(
    const u16* __restrict__ A, int lda, long sA1, long sA2,
    const u16* __restrict__ B, int ldb, long sB1, long sB2,
    u16* __restrict__ C, float* __restrict__ Cf, int ldc, long sC1, long sC2,
    int M, int N, int K, int zdiv,
    const float* __restrict__ bias, float scale, int flags)
{
    constexpr int NB   = (MODE == 0) ? 1 : (MODE == 1 ? 2 : 3);
    constexpr int BUFE = 128 * 32;
    __shared__ __align__(16) u16 As[NB * BUFE];
    __shared__ __align__(16) u16 Bs[NB * BUFE];

    const int z  = blockIdx.y;
    const int zb = z / zdiv, zh = z - zb * zdiv;
    const u16* Ab = A + (long)zb * sA1 + (long)zh * sA2;
    const u16* Bb = B + (long)zb * sB1 + (long)zh * sB2;
    u16*   Cb  = C  ? C  + (long)zb * sC1 + (long)zh * sC2 : nullptr;
    float* Cfb = Cf ? Cf + (long)zb * sC1 + (long)zh * sC2 : nullptr;

    const int tilesN = N >> 7;
    const int tilesM = M >> 7;
    int tm, tn;
    if ((tilesM & 7) == 0) {
        // bijective XCD-grouping swizzle: tm % 8 == linear-wg % 8
        const int xcd = blockIdx.x & 7, idx = blockIdx.x >> 3;
        const int mg  = tilesM >> 3;
        tm = ((idx % mg) << 3) | xcd;
        tn = idx / mg;
    } else {
        tm = blockIdx.x / tilesN;
        tn = blockIdx.x - tm * tilesN;
    }
    const int m0 = tm << 7, n0 = tn << 7;

    const int tid  = threadIdx.x;
    const int lane = tid & 63;
    const int wave = tid >> 6;
    const int wm = (wave & 1) << 6, wn = (wave >> 1) << 6;
    const int quad = lane >> 4, l16 = lane & 15;

    f32x4 acc[4][4];
#pragma unroll
    for (int i = 0; i < 4; i++)
#pragma unroll
        for (int j = 0; j < 4; j++) acc[i][j] = (f32x4){0.f, 0.f, 0.f, 0.f};

    const int lrA = (wave << 5) + (lane >> 2);
    const int lc  = (lane & 3) << 3;
    const u16* gA0 = Ab + (long)(m0 + lrA) * lda + lc;
    const u16* gA1 = Ab + (long)(m0 + lrA + 16) * lda + lc;
    const u16* gB0 = Bb + (long)(n0 + lrA) * ldb + lc;
    const u16* gB1 = Bb + (long)(n0 + lrA + 16) * ldb + lc;
    u16* lA0 = As + ((wave << 5) +  0) * 32;
    u16* lA1 = As + ((wave << 5) + 16) * 32;
    u16* lB0 = Bs + ((wave << 5) +  0) * 32;
    u16* lB1 = Bs + ((wave << 5) + 16) * 32;

    auto STAGE = [&](int bi, int k0) {
        llds16(gA0 + k0, lA0 + bi * BUFE);
        llds16(gA1 + k0, lA1 + bi * BUFE);
        llds16(gB0 + k0, lB0 + bi * BUFE);
        llds16(gB1 + k0, lB1 + bi * BUFE);
    };
    auto COMPUTE = [&](int bi) {
        const u16* Ac = As + bi * BUFE;
        const u16* Bc = Bs + bi * BUFE;
        bf16x8 af[4], bfr[4];
#pragma unroll
        for (int t = 0; t < 4; t++)
            af[t] = *(const bf16x8*)(Ac + (wm + t * 16 + l16) * 32 + quad * 8);
#pragma unroll
        for (int t = 0; t < 4; t++)
            bfr[t] = *(const bf16x8*)(Bc + (wn + t * 16 + l16) * 32 + quad * 8);
        // operand-swapped: acc[i][j] holds C^T fragment ->
        //   acc[i][j][r] = C[m0+wm+i*16+l16][n0+wn+j*16+quad*4+r]
#pragma unroll
        for (int i = 0; i < 4; i++)
#pragma unroll
            for (int j = 0; j < 4; j++)
                acc[i][j] = __builtin_amdgcn_mfma_f32_16x16x32_bf16(
                    bfr[j], af[i], acc[i][j], 0, 0, 0);
    };

    if (MODE == 0) {
        for (int k0 = 0; k0 < K; k0 += 32) {
            __syncthreads();
            STAGE(0, k0);
            __syncthreads();
            COMPUTE(0);
        }
    } else if (MODE == 1) {
        STAGE(0, 0);
        __syncthreads();
        int cur = 0;
        for (int k0 = 0; k0 < K; k0 += 32) {
            const int nxt = cur ^ 1;
            if (k0 + 32 < K) STAGE(nxt, k0 + 32);
            COMPUTE(cur);
            __syncthreads();
            cur = nxt;
        }
    } else {
        // 3-buffer counted-vmcnt pipeline.  K >= 96 at all call sites.
        STAGE(0, 0);
        STAGE(1, 32);
        int cur = 0;
        for (int k0 = 0; k0 < K; k0 += 32) {
            // wait: my 4 DMA loads for tile cur (issued ~2 iters ago) done;
            // prior tile's ds_reads drained.  Tile cur+1's 4 loads stay in
            // flight across the barrier (vmcnt(4)), except at the tail.
            if (k0 + 32 < K) {
                asm volatile("s_waitcnt vmcnt(4) lgkmcnt(0)" ::: "memory");
            } else {
                asm volatile("s_waitcnt vmcnt(0) lgkmcnt(0)" ::: "memory");
            }
            __builtin_amdgcn_sched_barrier(0);
            __builtin_amdgcn_s_barrier();     // all waves: tile cur resident,
            __builtin_amdgcn_sched_barrier(0);//  prev-tile reads complete
            if (k0 + 64 < K) {
                int pre = cur + 2; if (pre >= 3) pre -= 3;
                STAGE(pre, k0 + 64);          // overwrites prev tile's buffer
            }
            COMPUTE(cur);
            cur = (cur == 2) ? 0 : cur + 1;
        }
    }

    // C^T epilogue: lane writes 4 consecutive cols per (i,j) -> u16x4/f32x4.
#pragma unroll
    for (int i = 0; i < 4; i++) {
        const long row = m0 + wm + i * 16 + l16;
#pragma unroll
        for (int j = 0; j < 4; j++) {
            const int col = n0 + wn + j * 16 + quad * 4;
            f32x4 bv = bias ? *(const f32x4*)(bias + col)
                            : (f32x4){0.f, 0.f, 0.f, 0.f};
            f32x4 v4;
#pragma unroll
            for (int r = 0; r < 4; r++) {
                float v = acc[i][j][r] * scale + bv[r];
                if (flags & 1)
                    v = 0.5f * v * (1.f + erff(v * 0.70710678118654752f));
                v4[r] = v;
            }
            if (Cfb) {
                *(f32x4*)(Cfb + row * ldc + col) = v4;
            } else {
                u16x4 ov;
#pragma unroll
                for (int r = 0; r < 4; r++) ov[r] = f2bf(v4[r]);
                *(u16x4*)(Cb + row * ldc + col) = ov;
            }
        }
    }
}

// ---------------------------------------------------------------------------
// Flash attention: O = softmax(scale*Q K^T + mask) V, head dim 64, L = 512.
//   Q: (b, 512, ldq) bf16, head h at cols h*64;  K: (b, 512, ldk) bf16
//   VT: (bh, 64, 512) bf16 (per-head V^T);  O: (b, 512, 1024) bf16
// grid (bh=cb*16, qt=8): bh FAST so the 8 qt-blocks of one head land on the
// SAME XCD (256 % 8 == 0) -> K/VT fetched once per XCD, L2-served after.
// Block: 4 waves, 64 q-rows; K-tile(128x64) + VT-tile(64x128) staged in LDS.
// Swapped-operand S^T = mfma(K,Q); softmax in-register (exp2, cvt_pk);
// zero-shuffle PV via key-permutation sigma; T14 async-STAGE.
// ---------------------------------------------------------------------------
__global__ __launch_bounds__(256, 4) void flash_kernel(
    const u16* __restrict__ Q, const u16* __restrict__ K,
    const u16* __restrict__ VT, u16* __restrict__ O,
    const float* __restrict__ mask, int causal, int ldq, int ldk)
{
    __shared__ __align__(16) u16 Ks[128 * 72];    // keys x dims, pad 64->72
    __shared__ __align__(16) u16 Vs[64 * 136];    // dims x keys, pad 128->136
    const int tid  = threadIdx.x;
    const int wave = tid >> 6, lane = tid & 63;
    const int quad = lane >> 4, l16 = lane & 15;
    const int bh = blockIdx.x, qt = blockIdx.y, b = bh >> 4, h = bh & 15;
    const int qbase = qt * 64 + wave * 16;
    const int qrow  = qbase + l16;            // this lane's q row

    const u16* qp = Q + ((long)b * LTOK + qrow) * ldq + h * 64 + quad * 8;
    bf16x8 aq0 = *(const bf16x8*)(qp);
    bf16x8 aq1 = *(const bf16x8*)(qp + 32);

    f32x4 oacc[4];
#pragma unroll
    for (int jd = 0; jd < 4; jd++) oacc[jd] = (f32x4){0.f, 0.f, 0.f, 0.f};
    float m_st = -3.0e38f;      // running max, log2 domain
    float l_st = 0.f;           // running denom

    const int krow = tid >> 3,       kcol = (tid & 7) << 3;   // K: 32 rows/issue
    const int vrow = tid >> 2,       vcol = (tid & 3) << 3;   // VT: 64 rows, 4x8 cols/issue
    const u16* gK = K + ((long)b * LTOK + krow) * ldk + h * 64 + kcol;
    const u16* gV = VT + ((long)bh * 64 + vrow) * LTOK + vcol;

    const float C1    = 0.125f * 1.44269504088896340736f;   // scale*log2(e)
    const float NEGL2 = -10000.0f * 1.44269504088896340736f;

    const int nkt = causal ? ((qt * 64 + 63) >> 7) + 1 : (LTOK >> 7);

    // ---- prologue: stage tile 0 ----
    u16x8 KR[4], VR[4];
#pragma unroll
    for (int i = 0; i < 4; i++) KR[i] = *(const u16x8*)(gK + (long)(i * 32) * ldk);
#pragma unroll
    for (int i = 0; i < 4; i++) VR[i] = *(const u16x8*)(gV + i * 32);
#pragma unroll
    for (int i = 0; i < 4; i++)
        *(u16x8*)(Ks + (i * 32 + krow) * 72 + kcol) = KR[i];
#pragma unroll
    for (int i = 0; i < 4; i++)
        *(u16x8*)(Vs + vrow * 136 + i * 32 + vcol) = VR[i];
    __syncthreads();

    for (int kt = 0; kt < nkt; kt++) {
        const int k0 = kt << 7;
        const bool more = (kt + 1 < nkt);     // block-uniform

        // T14: issue next tile's global loads now; write to LDS after compute
        if (more) {
            const int kn = k0 + 128;
#pragma unroll
            for (int i = 0; i < 4; i++)
                KR[i] = *(const u16x8*)(gK + (long)(kn + i * 32) * ldk);
#pragma unroll
            for (int i = 0; i < 4; i++)
                VR[i] = *(const u16x8*)(gV + kn + i * 32);
        }

        // S^T = K Q^T : C-layout col = l16 = q, row = key = j*16 + quad*4 + r
        f32x4 s[8];
#pragma unroll
        for (int j = 0; j < 8; j++) {
            bf16x8 bk0 = *(const bf16x8*)(Ks + (j * 16 + l16) * 72 + quad * 8);
            bf16x8 bk1 = *(const bf16x8*)(Ks + (j * 16 + l16) * 72 + 32 + quad * 8);
            f32x4 z = (f32x4){0.f, 0.f, 0.f, 0.f};
            z = __builtin_amdgcn_mfma_f32_16x16x32_bf16(bk0, aq0, z, 0, 0, 0);
            s[j] = __builtin_amdgcn_mfma_f32_16x16x32_bf16(bk1, aq1, z, 0, 0, 0);
        }

        float tm0 = -3.0e38f, tm1 = -3.0e38f, tm2 = -3.0e38f, tm3 = -3.0e38f;
#pragma unroll
        for (int j = 0; j < 8; j++) {
            if (causal) {
                f32x4 m4 = *(const f32x4*)(mask + (long)b * LTOK + k0 + j * 16 + quad * 4);
#pragma unroll
                for (int r = 0; r < 4; r++) {
                    int key = k0 + j * 16 + quad * 4 + r;
                    float ad = (key <= qrow) ? fmaf(m4[r], -NEGL2, NEGL2) : NEGL2;
                    s[j][r] = fmaf(s[j][r], C1, ad);
                }
            } else {
#pragma unroll
                for (int r = 0; r < 4; r++) s[j][r] *= C1;
            }
            tm0 = fmaxf(tm0, s[j][0]); tm1 = fmaxf(tm1, s[j][1]);
            tm2 = fmaxf(tm2, s[j][2]); tm3 = fmaxf(tm3, s[j][3]);
        }
        float tmax = fmaxf(fmaxf(tm0, tm1), fmaxf(tm2, tm3));
        tmax = fmaxf(tmax, __shfl_xor(tmax, 16));
        tmax = fmaxf(tmax, __shfl_xor(tmax, 32));

        float mnew  = fmaxf(m_st, tmax);
        float alpha = __builtin_amdgcn_exp2f(m_st - mnew);
        m_st = mnew;

        float rs0 = 0.f, rs1 = 0.f, rs2 = 0.f, rs3 = 0.f;
        unsigned pk[8][2];
#pragma unroll
        for (int j = 0; j < 8; j++) {
            float p0 = __builtin_amdgcn_exp2f(s[j][0] - mnew);
            float p1 = __builtin_amdgcn_exp2f(s[j][1] - mnew);
            float p2 = __builtin_amdgcn_exp2f(s[j][2] - mnew);
            float p3 = __builtin_amdgcn_exp2f(s[j][3] - mnew);
            rs0 += p0; rs1 += p1; rs2 += p2; rs3 += p3;
            asm("v_cvt_pk_bf16_f32 %0, %1, %2" : "=v"(pk[j][0]) : "v"(p0), "v"(p1));
            asm("v_cvt_pk_bf16_f32 %0, %1, %2" : "=v"(pk[j][1]) : "v"(p2), "v"(p3));
        }
        float rsum = (rs0 + rs1) + (rs2 + rs3);
        rsum += __shfl_xor(rsum, 16);
        rsum += __shfl_xor(rsum, 32);
        l_st = l_st * alpha + rsum;

#pragma unroll
        for (int jd = 0; jd < 4; jd++) oacc[jd] *= alpha;

        // O^T += V^T P^T under key-permutation sigma (zero shuffles)
#pragma unroll
        for (int kk = 0; kk < 4; kk++) {
            unsigned wv[4] = { pk[2 * kk][0], pk[2 * kk][1],
                               pk[2 * kk + 1][0], pk[2 * kk + 1][1] };
            bf16x8 bp; __builtin_memcpy(&bp, wv, 16);
#pragma unroll
            for (int jd = 0; jd < 4; jd++) {
                const u16* vb = Vs + (jd * 16 + l16) * 136 + kk * 32 + quad * 4;
                u16 va[8];
                *(u16x4*)(va)     = *(const u16x4*)(vb);
                *(u16x4*)(va + 4) = *(const u16x4*)(vb + 16);
                bf16x8 av; __builtin_memcpy(&av, va, 16);
                oacc[jd] = __builtin_amdgcn_mfma_f32_16x16x32_bf16(av, bp, oacc[jd], 0, 0, 0);
            }
        }

        if (more) {
            __syncthreads();    // all waves done reading current Ks/Vs
#pragma unroll
            for (int i = 0; i < 4; i++)
                *(u16x8*)(Ks + (i * 32 + krow) * 72 + kcol) = KR[i];
#pragma unroll
            for (int i = 0; i < 4; i++)
                *(u16x8*)(Vs + vrow * 136 + i * 32 + vcol) = VR[i];
            __syncthreads();
        }
    }

    // O^T element (d = jd*16 + quad*4 + r, q = l16): 4 consecutive cols/lane
    float linv = 1.f / l_st;
    long obase = ((long)b * LTOK + qrow) * DDIM + h * 64;
#pragma unroll
    for (int jd = 0; jd < 4; jd++) {
        u16x4 ov;
#pragma unroll
        for (int r = 0; r < 4; r++) ov[r] = f2bf(oacc[jd][r] * linv);
        *(u16x4*)(O + obase + jd * 16 + quad * 4) = ov;
    }
}

// out = LayerNorm(a + b) * g + beta.  a: bf16.  b: bf16 unless b32 (fp32).
// Output: bf16 (o) unless of != nullptr (fp32).  Row length 1024.
__global__ __launch_bounds__(256) void add_ln_kernel(
    const u16* __restrict__ a, const u16* __restrict__ b,
    const float* __restrict__ b32,
    const float* __restrict__ g, const float* __restrict__ bt,
    u16* __restrict__ o, float* __restrict__ of)
{
    long row = blockIdx.x;
    int tid = threadIdx.x;
    __shared__ float red[4];
    const u16* ar = a + row * DDIM;
    float xv[4]; float s = 0.f;
#pragma unroll
    for (int i = 0; i < 4; i++) {
        int c = tid + 256 * i;
        float sum = bf2f(ar[c]) + (b32 ? b32[row * DDIM + c] : bf2f(b[row * DDIM + c]));
        xv[i] = fminf(fmaxf(sum, -1.0e18f), 1.0e18f);
        s += xv[i];
    }
#pragma unroll
    for (int ofs = 32; ofs >= 1; ofs >>= 1) s += __shfl_xor(s, ofs);
    int wave = tid >> 6, lane = tid & 63;
    if (lane == 0) red[wave] = s;
    __syncthreads();
    float mu = (red[0] + red[1] + red[2] + red[3]) * (1.f / 1024.f);
    __syncthreads();
    float v = 0.f;
#pragma unroll
    for (int i = 0; i < 4; i++) { float d = xv[i] - mu; v += d * d; }
#pragma unroll
    for (int ofs = 32; ofs >= 1; ofs >>= 1) v += __shfl_xor(v, ofs);
    if (lane == 0) red[wave] = v;
    __syncthreads();
    float var = (red[0] + red[1] + red[2] + red[3]) * (1.f / 1024.f);
    float inv = rsqrtf(var + 1e-6f);
#pragma unroll
    for (int i = 0; i < 4; i++) {
        int c = tid + 256 * i;
        float r = (xv[i] - mu) * inv * g[c] + bt[c];
        if (of) of[row * DDIM + c] = r;
        else    o [row * DDIM + c] = f2bf(r);
    }
}

// fp32 -> bf16 conversion, 8 elements/thread.
__global__ __launch_bounds__(256) void cvt_kernel(
    const float* __restrict__ src, u16* __restrict__ dst)
{
    long i = ((long)blockIdx.x * 256 + threadIdx.x) * 8;
    u16x8 o;
#pragma unroll
    for (int j = 0; j < 8; j++) o[j] = f2bf(src[i + j]);
    *(u16x8*)(dst + i) = o;
}

// Transpose+cvt the 8 fp32 weight matrices (1024x1024): WT[n][k] = bf16(W[k][n])
__global__ __launch_bounds__(256) void wt_kernel(
    const float* w0, const float* w1, const float* w2, const float* w3,
    const float* w4, const float* w5, const float* w6, const float* w7,
    u16* __restrict__ wt)
{
    const float* srcs[8] = {w0, w1, w2, w3, w4, w5, w6, w7};
    const float* w = srcs[blockIdx.z];
    u16* o = wt + (long)blockIdx.z * DDIM * DDIM;
    __shared__ u16 t[32][33];
    int tx = threadIdx.x & 31, ty = threadIdx.x >> 5;
    int c0 = blockIdx.x << 5, r0 = blockIdx.y << 5;
#pragma unroll
    for (int i = 0; i < 4; i++)
        t[ty + 8 * i][tx] = f2bf(w[(long)(r0 + ty + 8 * i) * DDIM + c0 + tx]);
    __syncthreads();
#pragma unroll
    for (int i = 0; i < 4; i++)
        o[(long)(c0 + ty + 8 * i) * DDIM + r0 + tx] = t[tx][ty + 8 * i];
}

// Concatenate up to 3 bias vectors (1024 each) into one fp32 array.
__global__ __launch_bounds__(256) void biascat_kernel(
    const float* __restrict__ b0, const float* __restrict__ b1,
    const float* __restrict__ b2, float* __restrict__ dst)
{
    int i = blockIdx.x * 256 + threadIdx.x;
    const float* s = (i < 1024) ? b0 : (i < 2048) ? b1 : b2;
    dst[i] = s[i & 1023];
}

// vt[(b*NH+h)*64 + dd][k] = v[b*LTOK + k][h*64 + dd]   (per-head V transpose)
__global__ __launch_bounds__(256) void vtrans_kernel(
    const u16* __restrict__ v, u16* __restrict__ vt, int ldv)
{
    int bh = blockIdx.y; int b = bh >> 4, h = bh & 15;
    int k0 = blockIdx.x << 5;
    __shared__ __align__(16) u16 t[32 * 72];
    int kk = threadIdx.x >> 3, c = (threadIdx.x & 7) << 3;
    u16x8 val = *(const u16x8*)(v + ((long)b * LTOK + k0 + kk) * ldv + h * 64 + c);
    *(u16x8*)(t + kk * 72 + c) = val;
    __syncthreads();
    int dd = threadIdx.x >> 2, k2 = (threadIdx.x & 3) << 3;
    u16x8 o;
#pragma unroll
    for (int j = 0; j < 8; j++) o[j] = t[(k2 + j) * 72 + dd];
    *(u16x8*)(vt + ((long)bh * 64 + dd) * LTOK + k0 + k2) = o;
}

extern "C" void kernel_launch(void* const* d_in, const int* in_sizes, int n_in,
                              void* d_out, int out_size, void* d_ws, size_t ws_size,
                              hipStream_t stream)
{
    const float* x     = (const float*)d_in[0];
    const float* dmsk  = (const float*)d_in[1];
    const float* enc   = (const float*)d_in[2];
    const float* sa_wq = (const float*)d_in[3];  const float* sa_bq = (const float*)d_in[4];
    const float* sa_wk = (const float*)d_in[5];  const float* sa_bk = (const float*)d_in[6];
    const float* sa_wv = (const float*)d_in[7];  const float* sa_bv = (const float*)d_in[8];
    const float* n1_g  = (const float*)d_in[9];  const float* n1_b  = (const float*)d_in[10];
    const float* ca_wq = (const float*)d_in[11]; const float* ca_bq = (const float*)d_in[12];
    const float* ca_wk = (const float*)d_in[13]; const float* ca_bk = (const float*)d_in[14];
    const float* ca_wv = (const float*)d_in[15]; const float* ca_bv = (const float*)d_in[16];
    const float* n2_g  = (const float*)d_in[17]; const float* n2_b  = (const float*)d_in[18];
    const float* int_w = (const float*)d_in[19]; const float* int_b = (const float*)d_in[20];
    const float* out_w = (const float*)d_in[21]; const float* out_b = (const float*)d_in[22];
    const float* out_g = (const float*)d_in[23]; const float* out_bt= (const float*)d_in[24];

    float* outp = (float*)d_out;
    float* visp = outp + (long)NBATCH * LTOK * DDIM;   // attention_vis (fp32)

    // --- workspace: chunk over batches; 7 buffer units / batch + WT + bias ---
    const size_t WTB  = (size_t)8 * DDIM * DDIM * 2;            // 16 MiB
    const size_t BUF1 = (size_t)LTOK * DDIM * 2;                // 1 MiB / batch
    int cb = 16;
    while (cb > 1 && WTB + (size_t)cb * 7 * BUF1 + 32768 > ws_size)
        cb >>= 1;

    char* ws = (char*)d_ws;
    size_t off = 0;
    auto alloc = [&](size_t bytes) -> u16* {
        u16* p = (u16*)(ws + off);
        off += (bytes + 255) & ~(size_t)255;
        return p;
    };
    u16* Xb  = alloc((size_t)cb * BUF1);          // Xb -> h
    u16* Eb  = alloc((size_t)cb * BUF1);          // Eb -> h2
    u16* Q3  = alloc((size_t)cb * 3 * BUF1);      // qkv(ld 3072) -> CQ | CKV -> I | G
    u16* Vt  = alloc((size_t)cb * BUF1);          // per-head V^T (self, then cross)
    u16* Cx  = alloc((size_t)cb * BUF1);          // attn ctx (self, then cross)
    u16* WT  = alloc(WTB);
    float* biasQKV = (float*)alloc(3072 * sizeof(float));
    float* biasKV  = (float*)alloc(2048 * sizeof(float));
    // no memset needed: every region fully written before read.

    u16* Wsaq = WT + 0L * DDIM * DDIM;   // [Wsaq|Wsak|Wsav] contiguous => fused B
    u16* Wcaq = WT + 3L * DDIM * DDIM;
    u16* Wcak = WT + 4L * DDIM * DDIM;   // [Wcak|Wcav] contiguous => fused B
    u16* Wint = WT + 6L * DDIM * DDIM;
    u16* Wout = WT + 7L * DDIM * DDIM;

    auto gemm = [&](const u16* A, int lda, long sA1, long sA2,
                    const u16* B, int ldb, long sB1, long sB2,
                    u16* C, float* Cf, int ldc, long sC1, long sC2,
                    int M, int N, int K, int Z, int zdiv,
                    const float* bias, float scale, int flags) {
        int tM = M / 128, tN = N / 128;
        long total = (long)tM * tN * Z;
        dim3 g(tM * tN, Z), blk(256);
        if (total >= 1536)       // >=6 blocks/CU: occupancy-limited -> 1-buf
            gemm_bt_kernel<0><<<g, blk, 0, stream>>>(
                A, lda, sA1, sA2, B, ldb, sB1, sB2, C, Cf, ldc, sC1, sC2,
                M, N, K, zdiv, bias, scale, flags);
        else if (total >= 1024)  // ~4/CU: 2-buf dbuf
            gemm_bt_kernel<1><<<g, blk, 0, stream>>>(
                A, lda, sA1, sA2, B, ldb, sB1, sB2, C, Cf, ldc, sC1, sC2,
                M, N, K, zdiv, bias, scale, flags);
        else                     // 1-2/CU: 3-buf counted-vmcnt pipeline
            gemm_bt_kernel<2><<<g, blk, 0, stream>>>(
                A, lda, sA1, sA2, B, ldb, sB1, sB2, C, Cf, ldc, sC1, sC2,
                M, N, K, zdiv, bias, scale, flags);
    };

    const long SLD = (long)LTOK * DDIM;       // per-batch row-block stride
    const long SSC = (long)LTOK * LTOK;       // vis elems per batch

    // 0) weight transposes + bf16 cvt + bias packs (once per call)
    wt_kernel<<<dim3(32, 32, 8), dim3(256), 0, stream>>>(
        sa_wq, sa_wk, sa_wv, ca_wq, ca_wk, ca_wv, int_w, out_w, WT);
    biascat_kernel<<<dim3(12), dim3(256), 0, stream>>>(sa_bq, sa_bk, sa_bv, biasQKV);
    biascat_kernel<<<dim3(8),  dim3(256), 0, stream>>>(ca_bk, ca_bv, ca_bv, biasKV);

    for (int b0 = 0; b0 < NBATCH; b0 += cb) {
        const float* xc = x   + (long)b0 * SLD;
        const float* ec = enc + (long)b0 * SLD;
        const int M = cb * LTOK;
        const int Z = cb * NH;
        const int cvtg = (int)(((long)M * DDIM) / (256 * 8));

        u16* h   = Xb;                                   // after QKV proj
        u16* CQ  = Q3;                                   // after self-attn
        u16* CKV = Q3 + (size_t)cb * LTOK * DDIM;        // cross k|v, ld 2048
        u16* I   = Q3;                                   // after cross-attn
        u16* G   = Q3 + (size_t)cb * LTOK * DDIM;
        u16* h2  = Eb;                                   // after cross proj

        // a) fp32 -> bf16 activation copies
        cvt_kernel<<<dim3(cvtg), dim3(256), 0, stream>>>(xc, Xb);
        cvt_kernel<<<dim3(cvtg), dim3(256), 0, stream>>>(ec, Eb);

        // 1) fused self-attn q|k|v projection: N=3072, ld 3072 (1536 blocks)
        gemm(Xb, DDIM, 0, 0, Wsaq, DDIM, 0, 0, Q3, nullptr, 3 * DDIM, 0, 0,
             M, 3 * DDIM, DDIM, 1, 1, biasQKV, 1.f, 0);
        vtrans_kernel<<<dim3(16, Z), dim3(256), 0, stream>>>(Q3 + 2 * DDIM, Vt, 3 * DDIM);

        // 2) self-attention (flash, causal+padding), ctx -> Cx
        flash_kernel<<<dim3(Z, 8), dim3(256), 0, stream>>>(
            Q3, Q3 + DDIM, Vt, Cx, dmsk + (long)b0 * LTOK, 1, 3 * DDIM, 3 * DDIM);

        // 3) h = LN(ctx + x_fp32) -> h (Xb reuse)
        add_ln_kernel<<<dim3(M), dim3(256), 0, stream>>>(
            Cx, nullptr, xc, n1_g, n1_b, h, nullptr);

        // 4) cq -> CQ;  fused cross k|v -> CKV (N=2048, ld 2048, 1024 blocks)
        gemm(h, DDIM, 0, 0, Wcaq, DDIM, 0, 0, CQ, nullptr, DDIM, 0, 0,
             M, DDIM, DDIM, 1, 1, ca_bq, 1.f, 0);
        gemm(Eb, DDIM, 0, 0, Wcak, DDIM, 0, 0, CKV, nullptr, 2 * DDIM, 0, 0,
             M, 2 * DDIM, DDIM, 1, 1, biasKV, 1.f, 0);

        // 5) attention_vis = (cq @ ck^T) / 128  -> fp32 d_out
        gemm(CQ, DDIM, SLD, 0, CKV, 2 * DDIM, (long)LTOK * 2 * DDIM, 0,
             nullptr, visp + (long)b0 * SSC, LTOK, SSC, 0,
             LTOK, LTOK, DDIM, cb, 1, nullptr, 1.f / 128.f, 0);

        // 6) cross-attention (flash, no mask): vt(cv)->Vt; ctx -> Cx
        vtrans_kernel<<<dim3(16, Z), dim3(256), 0, stream>>>(CKV + DDIM, Vt, 2 * DDIM);
        flash_kernel<<<dim3(Z, 8), dim3(256), 0, stream>>>(
            CQ, CKV, Vt, Cx, nullptr, 0, DDIM, 2 * DDIM);

        // 7) h2 = LN(h + cactx) -> h2 (Eb reuse)
        add_ln_kernel<<<dim3(M), dim3(256), 0, stream>>>(
            h, Cx, nullptr, n2_g, n2_b, h2, nullptr);

        // 8) inter = gelu(h2 @ int_w + int_b) -> I
        gemm(h2, DDIM, 0, 0, Wint, DDIM, 0, 0, I, nullptr, DDIM, 0, 0,
             M, DDIM, DDIM, 1, 1, int_b, 1.f, 1);
        // 9) G = inter @ out_w + out_b -> G
        gemm(I, DDIM, 0, 0, Wout, DDIM, 0, 0, G, nullptr, DDIM, 0, 0,
             M, DDIM, DDIM, 1, 1, out_b, 1.f, 0);
        // 10) out = LN(G + inter) -> fp32 d_out
        add_ln_kernel<<<dim3(M), dim3(256), 0, stream>>>(
            G, I, nullptr, out_g, out_bt, nullptr, outp + (long)b0 * SLD);
    }
}

// Round 6
// 564.048 us; speedup vs baseline: 1.0394x; 1.0394x over previous
//
#include <hip/hip_runtime.h>
#include <hip/hip_bf16.h>
#include <math.h>

// Problem constants
#define DDIM 1024
#define NH   16
#define LTOK 512
#define NBATCH 16

typedef unsigned short u16;
typedef unsigned short u16x8 __attribute__((ext_vector_type(8)));
typedef unsigned short u16x4 __attribute__((ext_vector_type(4)));
typedef __bf16 bf16x8 __attribute__((ext_vector_type(8)));
typedef float f32x4 __attribute__((ext_vector_type(4)));

typedef __attribute__((address_space(1))) void as1_void;
typedef __attribute__((address_space(3))) void as3_void;

__device__ __forceinline__ void llds16(const u16* g, u16* l) {
    // async 16B global->LDS DMA; LDS dest = wave-uniform base + lane*16B
    __builtin_amdgcn_global_load_lds((as1_void*)g, (as3_void*)l, 16, 0, 0);
}

__device__ __forceinline__ float bf2f(u16 u) {
    unsigned v = ((unsigned)u) << 16;
    float f; __builtin_memcpy(&f, &v, 4); return f;
}
__device__ __forceinline__ u16 f2bf(float f) {
    unsigned u; __builtin_memcpy(&u, &f, 4);
    u += 0x7fffu + ((u >> 16) & 1u);   // RNE
    return (u16)(u >> 16);
}

// One GEMM operand set:  C = act(scale*(A@B^T)+bias).  M,N multiples of 128,
// K multiple of 32 (all call sites comply).  nblk = (M/128)*(N/128)*Z.
struct GemmOp {
    const u16* A; const u16* B; u16* C; float* Cf; const float* bias;
    long sA1, sA2, sB1, sB2, sC1, sC2;
    int lda, ldb, ldc, M, N, K, zdiv, flags, nblk;
    float scale;
};

// ---------------------------------------------------------------------------
// Dual-op MFMA GEMM.  1-D grid; blocks [0, o1.nblk) run o1, the rest run o2
// (uniform per-block branch) -- merging independent GEMMs into one launch
// raises blocks/CU (the round-4/5 lesson: occupancy, not pipeline depth, is
// what the starved 512/256-block launches lack).
// MODE 0: single-buffer, 2 barriers/K-step (16KB LDS) -- >=6 blocks/CU.
// MODE 1: 2-buffer double-buffer, 1 barrier/K-step (32KB) -- smaller grids.
// Epilogue computes C^T fragments via mfma operand swap so each lane holds 4
// consecutive columns -> vectorized u16x4/f32x4 stores (less RMW).
// XCD swizzle (T1) when tilesM%8==0.
// ---------------------------------------------------------------------------
template<int MODE>
__global__ __launch_bounds__(256) void gemm_bt_kernel(GemmOp o1, GemmOp o2)
{
    constexpr int NB   = (MODE == 0) ? 1 : 2;
    constexpr int BUFE = 128 * 32;
    __shared__ __align__(16) u16 As[NB * BUFE];
    __shared__ __align__(16) u16 Bs[NB * BUFE];

    const bool second = (int)blockIdx.x >= o1.nblk;
    const GemmOp& o = second ? o2 : o1;
    int bidx = blockIdx.x - (second ? o1.nblk : 0);

    const int tilesN = o.N >> 7;
    const int tilesM = o.M >> 7;
    const int tiles  = tilesM * tilesN;
    const int z = bidx / tiles;
    const int t = bidx - z * tiles;
    const int zb = z / o.zdiv, zh = z - zb * o.zdiv;

    int tm, tn;
    if ((tilesM & 7) == 0) {
        // bijective XCD-grouping swizzle: tm % 8 == linear idx % 8
        const int xcd = t & 7, idx = t >> 3;
        const int mg  = tilesM >> 3;
        tm = ((idx % mg) << 3) | xcd;
        tn = idx / mg;
    } else {
        tm = t / tilesN;
        tn = t - tm * tilesN;
    }
    const int m0 = tm << 7, n0 = tn << 7;

    const u16* Ab = o.A + (long)zb * o.sA1 + (long)zh * o.sA2;
    const u16* Bb = o.B + (long)zb * o.sB1 + (long)zh * o.sB2;
    u16*   Cb  = o.C  ? o.C  + (long)zb * o.sC1 + (long)zh * o.sC2 : nullptr;
    float* Cfb = o.Cf ? o.Cf + (long)zb * o.sC1 + (long)zh * o.sC2 : nullptr;

    const int tid  = threadIdx.x;
    const int lane = tid & 63;
    const int wave = tid >> 6;
    const int wm = (wave & 1) << 6, wn = (wave >> 1) << 6;
    const int quad = lane >> 4, l16 = lane & 15;

    f32x4 acc[4][4];
#pragma unroll
    for (int i = 0; i < 4; i++)
#pragma unroll
        for (int j = 0; j < 4; j++) acc[i][j] = (f32x4){0.f, 0.f, 0.f, 0.f};

    const int lrA = (wave << 5) + (lane >> 2);
    const int lc  = (lane & 3) << 3;
    const u16* gA0 = Ab + (long)(m0 + lrA) * o.lda + lc;
    const u16* gA1 = Ab + (long)(m0 + lrA + 16) * o.lda + lc;
    const u16* gB0 = Bb + (long)(n0 + lrA) * o.ldb + lc;
    const u16* gB1 = Bb + (long)(n0 + lrA + 16) * o.ldb + lc;
    u16* lA0 = As + ((wave << 5) +  0) * 32;
    u16* lA1 = As + ((wave << 5) + 16) * 32;
    u16* lB0 = Bs + ((wave << 5) +  0) * 32;
    u16* lB1 = Bs + ((wave << 5) + 16) * 32;

    auto STAGE = [&](int bi, int k0) {
        llds16(gA0 + k0, lA0 + bi * BUFE);
        llds16(gA1 + k0, lA1 + bi * BUFE);
        llds16(gB0 + k0, lB0 + bi * BUFE);
        llds16(gB1 + k0, lB1 + bi * BUFE);
    };
    auto COMPUTE = [&](int bi) {
        const u16* Ac = As + bi * BUFE;
        const u16* Bc = Bs + bi * BUFE;
        bf16x8 af[4], bfr[4];
#pragma unroll
        for (int t2 = 0; t2 < 4; t2++)
            af[t2] = *(const bf16x8*)(Ac + (wm + t2 * 16 + l16) * 32 + quad * 8);
#pragma unroll
        for (int t2 = 0; t2 < 4; t2++)
            bfr[t2] = *(const bf16x8*)(Bc + (wn + t2 * 16 + l16) * 32 + quad * 8);
        // operand-swapped: acc[i][j] holds C^T fragment ->
        //   acc[i][j][r] = C[m0+wm+i*16+l16][n0+wn+j*16+quad*4+r]
#pragma unroll
        for (int i = 0; i < 4; i++)
#pragma unroll
            for (int j = 0; j < 4; j++)
                acc[i][j] = __builtin_amdgcn_mfma_f32_16x16x32_bf16(
                    bfr[j], af[i], acc[i][j], 0, 0, 0);
    };

    const int K = o.K;
    if (MODE == 0) {
        for (int k0 = 0; k0 < K; k0 += 32) {
            __syncthreads();
            STAGE(0, k0);
            __syncthreads();
            COMPUTE(0);
        }
    } else {
        STAGE(0, 0);
        __syncthreads();
        int cur = 0;
        for (int k0 = 0; k0 < K; k0 += 32) {
            const int nxt = cur ^ 1;
            if (k0 + 32 < K) STAGE(nxt, k0 + 32);
            COMPUTE(cur);
            __syncthreads();
            cur = nxt;
        }
    }

    // C^T epilogue: lane writes 4 consecutive cols per (i,j) -> u16x4/f32x4.
#pragma unroll
    for (int i = 0; i < 4; i++) {
        const long row = m0 + wm + i * 16 + l16;
#pragma unroll
        for (int j = 0; j < 4; j++) {
            const int col = n0 + wn + j * 16 + quad * 4;
            f32x4 bv = o.bias ? *(const f32x4*)(o.bias + col)
                              : (f32x4){0.f, 0.f, 0.f, 0.f};
            f32x4 v4;
#pragma unroll
            for (int r = 0; r < 4; r++) {
                float v = acc[i][j][r] * o.scale + bv[r];
                if (o.flags & 1)
                    v = 0.5f * v * (1.f + erff(v * 0.70710678118654752f));
                v4[r] = v;
            }
            if (Cfb) {
                *(f32x4*)(Cfb + row * o.ldc + col) = v4;
            } else {
                u16x4 ov;
#pragma unroll
                for (int r = 0; r < 4; r++) ov[r] = f2bf(v4[r]);
                *(u16x4*)(Cb + row * o.ldc + col) = ov;
            }
        }
    }
}

// ---------------------------------------------------------------------------
// Flash attention: O = softmax(scale*Q K^T + mask) V, head dim 64, L = 512.
//   Q: (b, 512, ldq) bf16, head h at cols h*64;  K: (b, 512, ldk) bf16
//   VT: (bh, 64, 512) bf16 (per-head V^T);  O: (b, 512, 1024) bf16
// grid (bh=cb*16, qt=8): bh FAST so the 8 qt-blocks of one head land on the
// SAME XCD (256 % 8 == 0) -> K/VT fetched once per XCD, L2-served after.
// Block: 4 waves, 64 q-rows; K-tile(128x64) + VT-tile(64x128) staged in LDS.
// Swapped-operand S^T = mfma(K,Q); softmax in-register (exp2, cvt_pk);
// zero-shuffle PV via key-permutation sigma; T14 async-STAGE.
// ---------------------------------------------------------------------------
__global__ __launch_bounds__(256, 4) void flash_kernel(
    const u16* __restrict__ Q, const u16* __restrict__ K,
    const u16* __restrict__ VT, u16* __restrict__ O,
    const float* __restrict__ mask, int causal, int ldq, int ldk)
{
    __shared__ __align__(16) u16 Ks[128 * 72];    // keys x dims, pad 64->72
    __shared__ __align__(16) u16 Vs[64 * 136];    // dims x keys, pad 128->136
    const int tid  = threadIdx.x;
    const int wave = tid >> 6, lane = tid & 63;
    const int quad = lane >> 4, l16 = lane & 15;
    const int bh = blockIdx.x, qt = blockIdx.y, b = bh >> 4, h = bh & 15;
    const int qbase = qt * 64 + wave * 16;
    const int qrow  = qbase + l16;            // this lane's q row

    const u16* qp = Q + ((long)b * LTOK + qrow) * ldq + h * 64 + quad * 8;
    bf16x8 aq0 = *(const bf16x8*)(qp);
    bf16x8 aq1 = *(const bf16x8*)(qp + 32);

    f32x4 oacc[4];
#pragma unroll
    for (int jd = 0; jd < 4; jd++) oacc[jd] = (f32x4){0.f, 0.f, 0.f, 0.f};
    float m_st = -3.0e38f;      // running max, log2 domain
    float l_st = 0.f;           // running denom

    const int krow = tid >> 3,       kcol = (tid & 7) << 3;   // K: 32 rows/issue
    const int vrow = tid >> 2,       vcol = (tid & 3) << 3;   // VT: 64 rows, 4x8 cols/issue
    const u16* gK = K + ((long)b * LTOK + krow) * ldk + h * 64 + kcol;
    const u16* gV = VT + ((long)bh * 64 + vrow) * LTOK + vcol;

    const float C1    = 0.125f * 1.44269504088896340736f;   // scale*log2(e)
    const float NEGL2 = -10000.0f * 1.44269504088896340736f;

    const int nkt = causal ? ((qt * 64 + 63) >> 7) + 1 : (LTOK >> 7);

    // ---- prologue: stage tile 0 ----
    u16x8 KR[4], VR[4];
#pragma unroll
    for (int i = 0; i < 4; i++) KR[i] = *(const u16x8*)(gK + (long)(i * 32) * ldk);
#pragma unroll
    for (int i = 0; i < 4; i++) VR[i] = *(const u16x8*)(gV + i * 32);
#pragma unroll
    for (int i = 0; i < 4; i++)
        *(u16x8*)(Ks + (i * 32 + krow) * 72 + kcol) = KR[i];
#pragma unroll
    for (int i = 0; i < 4; i++)
        *(u16x8*)(Vs + vrow * 136 + i * 32 + vcol) = VR[i];
    __syncthreads();

    for (int kt = 0; kt < nkt; kt++) {
        const int k0 = kt << 7;
        const bool more = (kt + 1 < nkt);     // block-uniform

        // T14: issue next tile's global loads now; write to LDS after compute
        if (more) {
            const int kn = k0 + 128;
#pragma unroll
            for (int i = 0; i < 4; i++)
                KR[i] = *(const u16x8*)(gK + (long)(kn + i * 32) * ldk);
#pragma unroll
            for (int i = 0; i < 4; i++)
                VR[i] = *(const u16x8*)(gV + kn + i * 32);
        }

        // S^T = K Q^T : C-layout col = l16 = q, row = key = j*16 + quad*4 + r
        f32x4 s[8];
#pragma unroll
        for (int j = 0; j < 8; j++) {
            bf16x8 bk0 = *(const bf16x8*)(Ks + (j * 16 + l16) * 72 + quad * 8);
            bf16x8 bk1 = *(const bf16x8*)(Ks + (j * 16 + l16) * 72 + 32 + quad * 8);
            f32x4 z = (f32x4){0.f, 0.f, 0.f, 0.f};
            z = __builtin_amdgcn_mfma_f32_16x16x32_bf16(bk0, aq0, z, 0, 0, 0);
            s[j] = __builtin_amdgcn_mfma_f32_16x16x32_bf16(bk1, aq1, z, 0, 0, 0);
        }

        float tm0 = -3.0e38f, tm1 = -3.0e38f, tm2 = -3.0e38f, tm3 = -3.0e38f;
#pragma unroll
        for (int j = 0; j < 8; j++) {
            if (causal) {
                f32x4 m4 = *(const f32x4*)(mask + (long)b * LTOK + k0 + j * 16 + quad * 4);
#pragma unroll
                for (int r = 0; r < 4; r++) {
                    int key = k0 + j * 16 + quad * 4 + r;
                    float ad = (key <= qrow) ? fmaf(m4[r], -NEGL2, NEGL2) : NEGL2;
                    s[j][r] = fmaf(s[j][r], C1, ad);
                }
            } else {
#pragma unroll
                for (int r = 0; r < 4; r++) s[j][r] *= C1;
            }
            tm0 = fmaxf(tm0, s[j][0]); tm1 = fmaxf(tm1, s[j][1]);
            tm2 = fmaxf(tm2, s[j][2]); tm3 = fmaxf(tm3, s[j][3]);
        }
        float tmax = fmaxf(fmaxf(tm0, tm1), fmaxf(tm2, tm3));
        tmax = fmaxf(tmax, __shfl_xor(tmax, 16));
        tmax = fmaxf(tmax, __shfl_xor(tmax, 32));

        float mnew  = fmaxf(m_st, tmax);
        float alpha = __builtin_amdgcn_exp2f(m_st - mnew);
        m_st = mnew;

        float rs0 = 0.f, rs1 = 0.f, rs2 = 0.f, rs3 = 0.f;
        unsigned pk[8][2];
#pragma unroll
        for (int j = 0; j < 8; j++) {
            float p0 = __builtin_amdgcn_exp2f(s[j][0] - mnew);
            float p1 = __builtin_amdgcn_exp2f(s[j][1] - mnew);
            float p2 = __builtin_amdgcn_exp2f(s[j][2] - mnew);
            float p3 = __builtin_amdgcn_exp2f(s[j][3] - mnew);
            rs0 += p0; rs1 += p1; rs2 += p2; rs3 += p3;
            asm("v_cvt_pk_bf16_f32 %0, %1, %2" : "=v"(pk[j][0]) : "v"(p0), "v"(p1));
            asm("v_cvt_pk_bf16_f32 %0, %1, %2" : "=v"(pk[j][1]) : "v"(p2), "v"(p3));
        }
        float rsum = (rs0 + rs1) + (rs2 + rs3);
        rsum += __shfl_xor(rsum, 16);
        rsum += __shfl_xor(rsum, 32);
        l_st = l_st * alpha + rsum;

#pragma unroll
        for (int jd = 0; jd < 4; jd++) oacc[jd] *= alpha;

        // O^T += V^T P^T under key-permutation sigma (zero shuffles)
#pragma unroll
        for (int kk = 0; kk < 4; kk++) {
            unsigned wv[4] = { pk[2 * kk][0], pk[2 * kk][1],
                               pk[2 * kk + 1][0], pk[2 * kk + 1][1] };
            bf16x8 bp; __builtin_memcpy(&bp, wv, 16);
#pragma unroll
            for (int jd = 0; jd < 4; jd++) {
                const u16* vb = Vs + (jd * 16 + l16) * 136 + kk * 32 + quad * 4;
                u16 va[8];
                *(u16x4*)(va)     = *(const u16x4*)(vb);
                *(u16x4*)(va + 4) = *(const u16x4*)(vb + 16);
                bf16x8 av; __builtin_memcpy(&av, va, 16);
                oacc[jd] = __builtin_amdgcn_mfma_f32_16x16x32_bf16(av, bp, oacc[jd], 0, 0, 0);
            }
        }

        if (more) {
            __syncthreads();    // all waves done reading current Ks/Vs
#pragma unroll
            for (int i = 0; i < 4; i++)
                *(u16x8*)(Ks + (i * 32 + krow) * 72 + kcol) = KR[i];
#pragma unroll
            for (int i = 0; i < 4; i++)
                *(u16x8*)(Vs + vrow * 136 + i * 32 + vcol) = VR[i];
            __syncthreads();
        }
    }

    // O^T element (d = jd*16 + quad*4 + r, q = l16): 4 consecutive cols/lane
    float linv = 1.f / l_st;
    long obase = ((long)b * LTOK + qrow) * DDIM + h * 64;
#pragma unroll
    for (int jd = 0; jd < 4; jd++) {
        u16x4 ov;
#pragma unroll
        for (int r = 0; r < 4; r++) ov[r] = f2bf(oacc[jd][r] * linv);
        *(u16x4*)(O + obase + jd * 16 + quad * 4) = ov;
    }
}

// out = LayerNorm(a + b) * g + beta.  a: bf16.  b: bf16 unless b32 (fp32).
// Output: bf16 (o) unless of != nullptr (fp32).  Row length 1024.
__global__ __launch_bounds__(256) void add_ln_kernel(
    const u16* __restrict__ a, const u16* __restrict__ b,
    const float* __restrict__ b32,
    const float* __restrict__ g, const float* __restrict__ bt,
    u16* __restrict__ o, float* __restrict__ of)
{
    long row = blockIdx.x;
    int tid = threadIdx.x;
    __shared__ float red[4];
    const u16* ar = a + row * DDIM;
    float xv[4]; float s = 0.f;
#pragma unroll
    for (int i = 0; i < 4; i++) {
        int c = tid + 256 * i;
        float sum = bf2f(ar[c]) + (b32 ? b32[row * DDIM + c] : bf2f(b[row * DDIM + c]));
        xv[i] = fminf(fmaxf(sum, -1.0e18f), 1.0e18f);
        s += xv[i];
    }
#pragma unroll
    for (int ofs = 32; ofs >= 1; ofs >>= 1) s += __shfl_xor(s, ofs);
    int wave = tid >> 6, lane = tid & 63;
    if (lane == 0) red[wave] = s;
    __syncthreads();
    float mu = (red[0] + red[1] + red[2] + red[3]) * (1.f / 1024.f);
    __syncthreads();
    float v = 0.f;
#pragma unroll
    for (int i = 0; i < 4; i++) { float d = xv[i] - mu; v += d * d; }
#pragma unroll
    for (int ofs = 32; ofs >= 1; ofs >>= 1) v += __shfl_xor(v, ofs);
    if (lane == 0) red[wave] = v;
    __syncthreads();
    float var = (red[0] + red[1] + red[2] + red[3]) * (1.f / 1024.f);
    float inv = rsqrtf(var + 1e-6f);
#pragma unroll
    for (int i = 0; i < 4; i++) {
        int c = tid + 256 * i;
        float r = (xv[i] - mu) * inv * g[c] + bt[c];
        if (of) of[row * DDIM + c] = r;
        else    o [row * DDIM + c] = f2bf(r);
    }
}

// fp32 -> bf16 conversion, 8 elements/thread.
__global__ __launch_bounds__(256) void cvt_kernel(
    const float* __restrict__ src, u16* __restrict__ dst)
{
    long i = ((long)blockIdx.x * 256 + threadIdx.x) * 8;
    u16x8 o;
#pragma unroll
    for (int j = 0; j < 8; j++) o[j] = f2bf(src[i + j]);
    *(u16x8*)(dst + i) = o;
}

// Transpose+cvt the 8 fp32 weight matrices (1024x1024): WT[n][k] = bf16(W[k][n])
__global__ __launch_bounds__(256) void wt_kernel(
    const float* w0, const float* w1, const float* w2, const float* w3,
    const float* w4, const float* w5, const float* w6, const float* w7,
    u16* __restrict__ wt)
{
    const float* srcs[8] = {w0, w1, w2, w3, w4, w5, w6, w7};
    const float* w = srcs[blockIdx.z];
    u16* o = wt + (long)blockIdx.z * DDIM * DDIM;
    __shared__ u16 t[32][33];
    int tx = threadIdx.x & 31, ty = threadIdx.x >> 5;
    int c0 = blockIdx.x << 5, r0 = blockIdx.y << 5;
#pragma unroll
    for (int i = 0; i < 4; i++)
        t[ty + 8 * i][tx] = f2bf(w[(long)(r0 + ty + 8 * i) * DDIM + c0 + tx]);
    __syncthreads();
#pragma unroll
    for (int i = 0; i < 4; i++)
        o[(long)(c0 + ty + 8 * i) * DDIM + r0 + tx] = t[tx][ty + 8 * i];
}

// Concatenate up to 3 bias vectors (1024 each) into one fp32 array.
__global__ __launch_bounds__(256) void biascat_kernel(
    const float* __restrict__ b0, const float* __restrict__ b1,
    const float* __restrict__ b2, float* __restrict__ dst)
{
    int i = blockIdx.x * 256 + threadIdx.x;
    const float* s = (i < 1024) ? b0 : (i < 2048) ? b1 : b2;
    dst[i] = s[i & 1023];
}

// vt[(b*NH+h)*64 + dd][k] = v[b*LTOK + k][h*64 + dd]   (per-head V transpose)
__global__ __launch_bounds__(256) void vtrans_kernel(
    const u16* __restrict__ v, u16* __restrict__ vt, int ldv)
{
    int bh = blockIdx.y; int b = bh >> 4, h = bh & 15;
    int k0 = blockIdx.x << 5;
    __shared__ __align__(16) u16 t[32 * 72];
    int kk = threadIdx.x >> 3, c = (threadIdx.x & 7) << 3;
    u16x8 val = *(const u16x8*)(v + ((long)b * LTOK + k0 + kk) * ldv + h * 64 + c);
    *(u16x8*)(t + kk * 72 + c) = val;
    __syncthreads();
    int dd = threadIdx.x >> 2, k2 = (threadIdx.x & 3) << 3;
    u16x8 o;
#pragma unroll
    for (int j = 0; j < 8; j++) o[j] = t[(k2 + j) * 72 + dd];
    *(u16x8*)(vt + ((long)bh * 64 + dd) * LTOK + k0 + k2) = o;
}

extern "C" void kernel_launch(void* const* d_in, const int* in_sizes, int n_in,
                              void* d_out, int out_size, void* d_ws, size_t ws_size,
                              hipStream_t stream)
{
    const float* x     = (const float*)d_in[0];
    const float* dmsk  = (const float*)d_in[1];
    const float* enc   = (const float*)d_in[2];
    const float* sa_wq = (const float*)d_in[3];  const float* sa_bq = (const float*)d_in[4];
    const float* sa_wk = (const float*)d_in[5];  const float* sa_bk = (const float*)d_in[6];
    const float* sa_wv = (const float*)d_in[7];  const float* sa_bv = (const float*)d_in[8];
    const float* n1_g  = (const float*)d_in[9];  const float* n1_b  = (const float*)d_in[10];
    const float* ca_wq = (const float*)d_in[11]; const float* ca_bq = (const float*)d_in[12];
    const float* ca_wk = (const float*)d_in[13]; const float* ca_bk = (const float*)d_in[14];
    const float* ca_wv = (const float*)d_in[15]; const float* ca_bv = (const float*)d_in[16];
    const float* n2_g  = (const float*)d_in[17]; const float* n2_b  = (const float*)d_in[18];
    const float* int_w = (const float*)d_in[19]; const float* int_b = (const float*)d_in[20];
    const float* out_w = (const float*)d_in[21]; const float* out_b = (const float*)d_in[22];
    const float* out_g = (const float*)d_in[23]; const float* out_bt= (const float*)d_in[24];

    float* outp = (float*)d_out;
    float* visp = outp + (long)NBATCH * LTOK * DDIM;   // attention_vis (fp32)

    // --- workspace: chunk over batches; 7 buffer units / batch + WT + bias ---
    const size_t WTB  = (size_t)8 * DDIM * DDIM * 2;            // 16 MiB
    const size_t BUF1 = (size_t)LTOK * DDIM * 2;                // 1 MiB / batch
    int cb = 16;
    while (cb > 1 && WTB + (size_t)cb * 7 * BUF1 + 32768 > ws_size)
        cb >>= 1;

    char* ws = (char*)d_ws;
    size_t off = 0;
    auto alloc = [&](size_t bytes) -> u16* {
        u16* p = (u16*)(ws + off);
        off += (bytes + 255) & ~(size_t)255;
        return p;
    };
    u16* Xb  = alloc((size_t)cb * BUF1);          // Xb -> h
    u16* Eb  = alloc((size_t)cb * BUF1);          // Eb -> h2
    u16* Q3  = alloc((size_t)cb * 3 * BUF1);      // qkv(ld 3072) -> CQ | CKV
    u16* Vt  = alloc((size_t)cb * BUF1);          // per-head V^T -> I
    u16* Cx  = alloc((size_t)cb * BUF1);          // attn ctx -> G
    u16* WT  = alloc(WTB);
    float* biasQKV = (float*)alloc(3072 * sizeof(float));
    float* biasKV  = (float*)alloc(2048 * sizeof(float));
    // no memset needed: every region fully written before read.

    u16* Wsaq = WT + 0L * DDIM * DDIM;   // [Wsaq|Wsak|Wsav] contiguous => fused B
    u16* Wcaq = WT + 3L * DDIM * DDIM;
    u16* Wcak = WT + 4L * DDIM * DDIM;   // [Wcak|Wcav] contiguous => fused B
    u16* Wint = WT + 6L * DDIM * DDIM;
    u16* Wout = WT + 7L * DDIM * DDIM;

    // op builder: simple (Z=1) dense GEMM C[M x N] = A[M x K] @ B[N x K]^T
    auto mkop = [](const u16* A, int lda, const u16* B, int ldb,
                   u16* C, float* Cf, int ldc, int M, int N, int K,
                   const float* bias, float scale, int flags) -> GemmOp {
        GemmOp o{};
        o.A = A; o.B = B; o.C = C; o.Cf = Cf; o.bias = bias;
        o.sA1 = 0; o.sA2 = 0; o.sB1 = 0; o.sB2 = 0; o.sC1 = 0; o.sC2 = 0;
        o.lda = lda; o.ldb = ldb; o.ldc = ldc; o.M = M; o.N = N; o.K = K;
        o.zdiv = 1; o.flags = flags; o.nblk = (M / 128) * (N / 128);
        o.scale = scale;
        return o;
    };

    auto launch = [&](GemmOp o1, GemmOp o2) {
        int nb = o1.nblk + o2.nblk;
        if (nb >= 1536)
            gemm_bt_kernel<0><<<dim3(nb), dim3(256), 0, stream>>>(o1, o2);
        else
            gemm_bt_kernel<1><<<dim3(nb), dim3(256), 0, stream>>>(o1, o2);
    };
    GemmOp nil{};   // nblk = 0

    const long SLD = (long)LTOK * DDIM;       // per-batch row-block stride
    const long SSC = (long)LTOK * LTOK;       // vis elems per batch

    // 0) weight transposes + bf16 cvt + bias packs (once per call)
    wt_kernel<<<dim3(32, 32, 8), dim3(256), 0, stream>>>(
        sa_wq, sa_wk, sa_wv, ca_wq, ca_wk, ca_wv, int_w, out_w, WT);
    biascat_kernel<<<dim3(12), dim3(256), 0, stream>>>(sa_bq, sa_bk, sa_bv, biasQKV);
    biascat_kernel<<<dim3(8),  dim3(256), 0, stream>>>(ca_bk, ca_bv, ca_bv, biasKV);

    for (int b0 = 0; b0 < NBATCH; b0 += cb) {
        const float* xc = x   + (long)b0 * SLD;
        const float* ec = enc + (long)b0 * SLD;
        const int M = cb * LTOK;
        const int Z = cb * NH;
        const int cvtg = (int)(((long)M * DDIM) / (256 * 8));

        u16* h   = Xb;                                   // LN1 out (Xb reuse)
        u16* CQ  = Q3;                                   // cross q
        u16* CKV = Q3 + (size_t)cb * LTOK * DDIM;        // cross k|v, ld 2048
        u16* I   = Vt;                                   // gelu FFN out (Vt reuse)
        u16* G   = Cx;                                   // out proj (Cx reuse)
        u16* h2  = Eb;                                   // LN2 out (Eb reuse)

        // a) fp32 -> bf16 activation copies
        cvt_kernel<<<dim3(cvtg), dim3(256), 0, stream>>>(xc, Xb);
        cvt_kernel<<<dim3(cvtg), dim3(256), 0, stream>>>(ec, Eb);

        // 1) fused self-attn q|k|v projection: N=3072 (1536 blocks, MODE0)
        launch(mkop(Xb, DDIM, Wsaq, DDIM, Q3, nullptr, 3 * DDIM,
                    M, 3 * DDIM, DDIM, biasQKV, 1.f, 0), nil);
        vtrans_kernel<<<dim3(16, Z), dim3(256), 0, stream>>>(Q3 + 2 * DDIM, Vt, 3 * DDIM);

        // 2) self-attention (flash, causal+padding), ctx -> Cx
        flash_kernel<<<dim3(Z, 8), dim3(256), 0, stream>>>(
            Q3, Q3 + DDIM, Vt, Cx, dmsk + (long)b0 * LTOK, 1, 3 * DDIM, 3 * DDIM);

        // 3) h = LN(ctx + x_fp32) -> h (Xb reuse)
        add_ln_kernel<<<dim3(M), dim3(256), 0, stream>>>(
            Cx, nullptr, xc, n1_g, n1_b, h, nullptr);

        // 4) MERGED cq | cross-k|v: 512 + 1024 = 1536 blocks -> MODE0
        launch(mkop(h,  DDIM, Wcaq, DDIM, CQ,  nullptr, DDIM,
                    M, DDIM, DDIM, ca_bq, 1.f, 0),
               mkop(Eb, DDIM, Wcak, DDIM, CKV, nullptr, 2 * DDIM,
                    M, 2 * DDIM, DDIM, biasKV, 1.f, 0));

        // 5) cross-attention (flash, no mask): vt(cv)->Vt; ctx -> Cx
        vtrans_kernel<<<dim3(16, Z), dim3(256), 0, stream>>>(CKV + DDIM, Vt, 2 * DDIM);
        flash_kernel<<<dim3(Z, 8), dim3(256), 0, stream>>>(
            CQ, CKV, Vt, Cx, nullptr, 0, DDIM, 2 * DDIM);

        // 6) h2 = LN(h + cactx) -> h2 (Eb reuse)
        add_ln_kernel<<<dim3(M), dim3(256), 0, stream>>>(
            h, Cx, nullptr, n2_g, n2_b, h2, nullptr);

        // 7) MERGED vis | int: 256 + 512 = 768 blocks -> MODE1 (3/CU).
        //    vis = (cq @ ck^T)/128 (batched over cb via strides, fp32 out);
        //    int = gelu(h2 @ int_w + int_b) -> I (Vt reuse; flash2 done).
        GemmOp ovis{};
        ovis.A = CQ;  ovis.lda = DDIM;     ovis.sA1 = SLD;               ovis.sA2 = 0;
        ovis.B = CKV; ovis.ldb = 2 * DDIM; ovis.sB1 = (long)LTOK * 2 * DDIM; ovis.sB2 = 0;
        ovis.C = nullptr; ovis.Cf = visp + (long)b0 * SSC;
        ovis.ldc = LTOK; ovis.sC1 = SSC; ovis.sC2 = 0;
        ovis.M = LTOK; ovis.N = LTOK; ovis.K = DDIM; ovis.zdiv = 1;
        ovis.bias = nullptr; ovis.scale = 1.f / 128.f; ovis.flags = 0;
        ovis.nblk = (LTOK / 128) * (LTOK / 128) * cb;     // 16 * cb
        launch(ovis,
               mkop(h2, DDIM, Wint, DDIM, I, nullptr, DDIM,
                    M, DDIM, DDIM, int_b, 1.f, 1));

        // 8) G = inter @ out_w + out_b -> G (Cx reuse; LN2 consumed Cx)
        launch(mkop(I, DDIM, Wout, DDIM, G, nullptr, DDIM,
                    M, DDIM, DDIM, out_b, 1.f, 0), nil);

        // 9) out = LN(G + inter) -> fp32 d_out
        add_ln_kernel<<<dim3(M), dim3(256), 0, stream>>>(
            G, I, nullptr, out_g, out_bt, nullptr, outp + (long)b0 * SLD);
    }
}

// Round 7
// 548.767 us; speedup vs baseline: 1.0684x; 1.0278x over previous
//
#include <hip/hip_runtime.h>
#include <hip/hip_bf16.h>
#include <math.h>

// Problem constants
#define DDIM 1024
#define NH   16
#define LTOK 512
#define NBATCH 16

typedef unsigned short u16;
typedef unsigned short u16x8 __attribute__((ext_vector_type(8)));
typedef unsigned short u16x4 __attribute__((ext_vector_type(4)));
typedef __bf16 bf16x8 __attribute__((ext_vector_type(8)));
typedef float f32x4 __attribute__((ext_vector_type(4)));

typedef __attribute__((address_space(1))) void as1_void;
typedef __attribute__((address_space(3))) void as3_void;

__device__ __forceinline__ void llds16(const u16* g, u16* l) {
    // async 16B global->LDS DMA; LDS dest = wave-uniform base + lane*16B
    __builtin_amdgcn_global_load_lds((as1_void*)g, (as3_void*)l, 16, 0, 0);
}

__device__ __forceinline__ float bf2f(u16 u) {
    unsigned v = ((unsigned)u) << 16;
    float f; __builtin_memcpy(&f, &v, 4); return f;
}
__device__ __forceinline__ u16 f2bf(float f) {
    unsigned u; __builtin_memcpy(&u, &f, 4);
    u += 0x7fffu + ((u >> 16) & 1u);   // RNE
    return (u16)(u >> 16);
}

// One GEMM operand set:  C = act(scale*(A@B^T)+bias).  M,N multiples of 128,
// K multiple of 32 (all call sites comply).  nblk = (M/128)*(N/128)*Z.
// If VTp != nullptr, output columns >= vtcol0 are per-head V projections and
// are written TRANSPOSED to VTp[((row/512)*NH + h)*64 + dd][row%512] instead
// of C (nothing reads V in row layout; flash consumes VT only).
struct GemmOp {
    const u16* A; const u16* B; u16* C; float* Cf; const float* bias;
    u16* VTp;
    long sA1, sA2, sB1, sB2, sC1, sC2;
    int lda, ldb, ldc, M, N, K, zdiv, flags, nblk, vtcol0;
    float scale;
};

// ---------------------------------------------------------------------------
// Dual-op MFMA GEMM.  1-D grid; blocks [0, o1.nblk) run o1, the rest run o2
// (uniform per-block branch) -- merging independent GEMMs raises blocks/CU.
// MODE 0: single-buffer, 2 barriers/K-step (16KB LDS).  Staging is issued and
//         immediately drained (pre-barrier vmcnt(0)) -> pays latency per step
//         but keeps 6 blocks/CU.
// MODE 1: 2-buffer double-buffer, 1 barrier/K-step (32KB, 5 blocks/CU) --
//         next tile's DMA is in flight across the whole compute phase.
// [A/B this round: QKV = MODE0 control, cq|cKV = MODE1 challenger.]
// Epilogue computes C^T fragments via mfma operand swap -> each lane holds 4
// consecutive columns -> vectorized u16x4/f32x4 stores; V-column tiles are
// redirected to the per-head transposed VT layout (kills vtrans kernels).
// XCD swizzle (T1) when tilesM%8==0.
// ---------------------------------------------------------------------------
template<int MODE>
__global__ __launch_bounds__(256) void gemm_bt_kernel(GemmOp o1, GemmOp o2)
{
    constexpr int NB   = (MODE == 0) ? 1 : 2;
    constexpr int BUFE = 128 * 32;
    __shared__ __align__(16) u16 As[NB * BUFE];
    __shared__ __align__(16) u16 Bs[NB * BUFE];

    const bool second = (int)blockIdx.x >= o1.nblk;
    const GemmOp& o = second ? o2 : o1;
    int bidx = blockIdx.x - (second ? o1.nblk : 0);

    const int tilesN = o.N >> 7;
    const int tilesM = o.M >> 7;
    const int tiles  = tilesM * tilesN;
    const int z = bidx / tiles;
    const int t = bidx - z * tiles;
    const int zb = z / o.zdiv, zh = z - zb * o.zdiv;

    int tm, tn;
    if ((tilesM & 7) == 0) {
        // bijective XCD-grouping swizzle: tm % 8 == linear idx % 8
        const int xcd = t & 7, idx = t >> 3;
        const int mg  = tilesM >> 3;
        tm = ((idx % mg) << 3) | xcd;
        tn = idx / mg;
    } else {
        tm = t / tilesN;
        tn = t - tm * tilesN;
    }
    const int m0 = tm << 7, n0 = tn << 7;

    const u16* Ab = o.A + (long)zb * o.sA1 + (long)zh * o.sA2;
    const u16* Bb = o.B + (long)zb * o.sB1 + (long)zh * o.sB2;
    u16*   Cb  = o.C  ? o.C  + (long)zb * o.sC1 + (long)zh * o.sC2 : nullptr;
    float* Cfb = o.Cf ? o.Cf + (long)zb * o.sC1 + (long)zh * o.sC2 : nullptr;

    const int tid  = threadIdx.x;
    const int lane = tid & 63;
    const int wave = tid >> 6;
    const int wm = (wave & 1) << 6, wn = (wave >> 1) << 6;
    const int quad = lane >> 4, l16 = lane & 15;

    f32x4 acc[4][4];
#pragma unroll
    for (int i = 0; i < 4; i++)
#pragma unroll
        for (int j = 0; j < 4; j++) acc[i][j] = (f32x4){0.f, 0.f, 0.f, 0.f};

    const int lrA = (wave << 5) + (lane >> 2);
    const int lc  = (lane & 3) << 3;
    const u16* gA0 = Ab + (long)(m0 + lrA) * o.lda + lc;
    const u16* gA1 = Ab + (long)(m0 + lrA + 16) * o.lda + lc;
    const u16* gB0 = Bb + (long)(n0 + lrA) * o.ldb + lc;
    const u16* gB1 = Bb + (long)(n0 + lrA + 16) * o.ldb + lc;
    u16* lA0 = As + ((wave << 5) +  0) * 32;
    u16* lA1 = As + ((wave << 5) + 16) * 32;
    u16* lB0 = Bs + ((wave << 5) +  0) * 32;
    u16* lB1 = Bs + ((wave << 5) + 16) * 32;

    auto STAGE = [&](int bi, int k0) {
        llds16(gA0 + k0, lA0 + bi * BUFE);
        llds16(gA1 + k0, lA1 + bi * BUFE);
        llds16(gB0 + k0, lB0 + bi * BUFE);
        llds16(gB1 + k0, lB1 + bi * BUFE);
    };
    auto COMPUTE = [&](int bi) {
        const u16* Ac = As + bi * BUFE;
        const u16* Bc = Bs + bi * BUFE;
        bf16x8 af[4], bfr[4];
#pragma unroll
        for (int t2 = 0; t2 < 4; t2++)
            af[t2] = *(const bf16x8*)(Ac + (wm + t2 * 16 + l16) * 32 + quad * 8);
#pragma unroll
        for (int t2 = 0; t2 < 4; t2++)
            bfr[t2] = *(const bf16x8*)(Bc + (wn + t2 * 16 + l16) * 32 + quad * 8);
        // operand-swapped: acc[i][j] holds C^T fragment ->
        //   acc[i][j][r] = C[m0+wm+i*16+l16][n0+wn+j*16+quad*4+r]
#pragma unroll
        for (int i = 0; i < 4; i++)
#pragma unroll
            for (int j = 0; j < 4; j++)
                acc[i][j] = __builtin_amdgcn_mfma_f32_16x16x32_bf16(
                    bfr[j], af[i], acc[i][j], 0, 0, 0);
    };

    const int K = o.K;
    if (MODE == 0) {
        for (int k0 = 0; k0 < K; k0 += 32) {
            __syncthreads();
            STAGE(0, k0);
            __syncthreads();
            COMPUTE(0);
        }
    } else {
        STAGE(0, 0);
        __syncthreads();
        int cur = 0;
        for (int k0 = 0; k0 < K; k0 += 32) {
            const int nxt = cur ^ 1;
            if (k0 + 32 < K) STAGE(nxt, k0 + 32);
            COMPUTE(cur);
            __syncthreads();
            cur = nxt;
        }
    }

    // C^T epilogue: lane writes 4 consecutive cols per (i,j).
    // V-column tiles (col >= vtcol0, tile-uniform) go transposed to VT.
#pragma unroll
    for (int i = 0; i < 4; i++) {
        const long row = m0 + wm + i * 16 + l16;
#pragma unroll
        for (int j = 0; j < 4; j++) {
            const int col = n0 + wn + j * 16 + quad * 4;
            f32x4 bv = o.bias ? *(const f32x4*)(o.bias + col)
                              : (f32x4){0.f, 0.f, 0.f, 0.f};
            f32x4 v4;
#pragma unroll
            for (int r = 0; r < 4; r++) {
                float v = acc[i][j][r] * o.scale + bv[r];
                if (o.flags & 1)
                    v = 0.5f * v * (1.f + erff(v * 0.70710678118654752f));
                v4[r] = v;
            }
            if (o.VTp && col >= o.vtcol0) {
                const int dv  = col - o.vtcol0;          // head h = dv>>6
                const long bh = (row >> 9) * NH + (dv >> 6);
                const int tok = (int)(row & (LTOK - 1));
                u16* vp = o.VTp + (bh * 64 + (dv & 63)) * LTOK + tok;
#pragma unroll
                for (int r = 0; r < 4; r++)
                    vp[(long)r * LTOK] = f2bf(v4[r]);
            } else if (Cfb) {
                *(f32x4*)(Cfb + row * o.ldc + col) = v4;
            } else {
                u16x4 ov;
#pragma unroll
                for (int r = 0; r < 4; r++) ov[r] = f2bf(v4[r]);
                *(u16x4*)(Cb + row * o.ldc + col) = ov;
            }
        }
    }
}

// ---------------------------------------------------------------------------
// Flash attention: O = softmax(scale*Q K^T + mask) V, head dim 64, L = 512.
//   Q: (b, 512, ldq) bf16, head h at cols h*64;  K: (b, 512, ldk) bf16
//   VT: (bh, 64, 512) bf16 (per-head V^T);  O: (b, 512, 1024) bf16
// grid (bh=cb*16, qt=8): bh FAST so the 8 qt-blocks of one head land on the
// SAME XCD (256 % 8 == 0) -> K/VT fetched once per XCD, L2-served after.
// Block: 4 waves, 64 q-rows; K-tile(128x64) + VT-tile(64x128) staged in LDS.
// Swapped-operand S^T = mfma(K,Q); softmax in-register (exp2, cvt_pk);
// zero-shuffle PV via key-permutation sigma; T14 async-STAGE.
// ---------------------------------------------------------------------------
__global__ __launch_bounds__(256, 4) void flash_kernel(
    const u16* __restrict__ Q, const u16* __restrict__ K,
    const u16* __restrict__ VT, u16* __restrict__ O,
    const float* __restrict__ mask, int causal, int ldq, int ldk)
{
    __shared__ __align__(16) u16 Ks[128 * 72];    // keys x dims, pad 64->72
    __shared__ __align__(16) u16 Vs[64 * 136];    // dims x keys, pad 128->136
    const int tid  = threadIdx.x;
    const int wave = tid >> 6, lane = tid & 63;
    const int quad = lane >> 4, l16 = lane & 15;
    const int bh = blockIdx.x, qt = blockIdx.y, b = bh >> 4, h = bh & 15;
    const int qbase = qt * 64 + wave * 16;
    const int qrow  = qbase + l16;            // this lane's q row

    const u16* qp = Q + ((long)b * LTOK + qrow) * ldq + h * 64 + quad * 8;
    bf16x8 aq0 = *(const bf16x8*)(qp);
    bf16x8 aq1 = *(const bf16x8*)(qp + 32);

    f32x4 oacc[4];
#pragma unroll
    for (int jd = 0; jd < 4; jd++) oacc[jd] = (f32x4){0.f, 0.f, 0.f, 0.f};
    float m_st = -3.0e38f;      // running max, log2 domain
    float l_st = 0.f;           // running denom

    const int krow = tid >> 3,       kcol = (tid & 7) << 3;   // K: 32 rows/issue
    const int vrow = tid >> 2,       vcol = (tid & 3) << 3;   // VT: 64 rows, 4x8 cols/issue
    const u16* gK = K + ((long)b * LTOK + krow) * ldk + h * 64 + kcol;
    const u16* gV = VT + ((long)bh * 64 + vrow) * LTOK + vcol;

    const float C1    = 0.125f * 1.44269504088896340736f;   // scale*log2(e)
    const float NEGL2 = -10000.0f * 1.44269504088896340736f;

    const int nkt = causal ? ((qt * 64 + 63) >> 7) + 1 : (LTOK >> 7);

    // ---- prologue: stage tile 0 ----
    u16x8 KR[4], VR[4];
#pragma unroll
    for (int i = 0; i < 4; i++) KR[i] = *(const u16x8*)(gK + (long)(i * 32) * ldk);
#pragma unroll
    for (int i = 0; i < 4; i++) VR[i] = *(const u16x8*)(gV + i * 32);
#pragma unroll
    for (int i = 0; i < 4; i++)
        *(u16x8*)(Ks + (i * 32 + krow) * 72 + kcol) = KR[i];
#pragma unroll
    for (int i = 0; i < 4; i++)
        *(u16x8*)(Vs + vrow * 136 + i * 32 + vcol) = VR[i];
    __syncthreads();

    for (int kt = 0; kt < nkt; kt++) {
        const int k0 = kt << 7;
        const bool more = (kt + 1 < nkt);     // block-uniform

        // T14: issue next tile's global loads now; write to LDS after compute
        if (more) {
            const int kn = k0 + 128;
#pragma unroll
            for (int i = 0; i < 4; i++)
                KR[i] = *(const u16x8*)(gK + (long)(kn + i * 32) * ldk);
#pragma unroll
            for (int i = 0; i < 4; i++)
                VR[i] = *(const u16x8*)(gV + kn + i * 32);
        }

        // S^T = K Q^T : C-layout col = l16 = q, row = key = j*16 + quad*4 + r
        f32x4 s[8];
#pragma unroll
        for (int j = 0; j < 8; j++) {
            bf16x8 bk0 = *(const bf16x8*)(Ks + (j * 16 + l16) * 72 + quad * 8);
            bf16x8 bk1 = *(const bf16x8*)(Ks + (j * 16 + l16) * 72 + 32 + quad * 8);
            f32x4 z = (f32x4){0.f, 0.f, 0.f, 0.f};
            z = __builtin_amdgcn_mfma_f32_16x16x32_bf16(bk0, aq0, z, 0, 0, 0);
            s[j] = __builtin_amdgcn_mfma_f32_16x16x32_bf16(bk1, aq1, z, 0, 0, 0);
        }

        float tm0 = -3.0e38f, tm1 = -3.0e38f, tm2 = -3.0e38f, tm3 = -3.0e38f;
#pragma unroll
        for (int j = 0; j < 8; j++) {
            if (causal) {
                f32x4 m4 = *(const f32x4*)(mask + (long)b * LTOK + k0 + j * 16 + quad * 4);
#pragma unroll
                for (int r = 0; r < 4; r++) {
                    int key = k0 + j * 16 + quad * 4 + r;
                    float ad = (key <= qrow) ? fmaf(m4[r], -NEGL2, NEGL2) : NEGL2;
                    s[j][r] = fmaf(s[j][r], C1, ad);
                }
            } else {
#pragma unroll
                for (int r = 0; r < 4; r++) s[j][r] *= C1;
            }
            tm0 = fmaxf(tm0, s[j][0]); tm1 = fmaxf(tm1, s[j][1]);
            tm2 = fmaxf(tm2, s[j][2]); tm3 = fmaxf(tm3, s[j][3]);
        }
        float tmax = fmaxf(fmaxf(tm0, tm1), fmaxf(tm2, tm3));
        tmax = fmaxf(tmax, __shfl_xor(tmax, 16));
        tmax = fmaxf(tmax, __shfl_xor(tmax, 32));

        float mnew  = fmaxf(m_st, tmax);
        float alpha = __builtin_amdgcn_exp2f(m_st - mnew);
        m_st = mnew;

        float rs0 = 0.f, rs1 = 0.f, rs2 = 0.f, rs3 = 0.f;
        unsigned pk[8][2];
#pragma unroll
        for (int j = 0; j < 8; j++) {
            float p0 = __builtin_amdgcn_exp2f(s[j][0] - mnew);
            float p1 = __builtin_amdgcn_exp2f(s[j][1] - mnew);
            float p2 = __builtin_amdgcn_exp2f(s[j][2] - mnew);
            float p3 = __builtin_amdgcn_exp2f(s[j][3] - mnew);
            rs0 += p0; rs1 += p1; rs2 += p2; rs3 += p3;
            asm("v_cvt_pk_bf16_f32 %0, %1, %2" : "=v"(pk[j][0]) : "v"(p0), "v"(p1));
            asm("v_cvt_pk_bf16_f32 %0, %1, %2" : "=v"(pk[j][1]) : "v"(p2), "v"(p3));
        }
        float rsum = (rs0 + rs1) + (rs2 + rs3);
        rsum += __shfl_xor(rsum, 16);
        rsum += __shfl_xor(rsum, 32);
        l_st = l_st * alpha + rsum;

#pragma unroll
        for (int jd = 0; jd < 4; jd++) oacc[jd] *= alpha;

        // O^T += V^T P^T under key-permutation sigma (zero shuffles)
#pragma unroll
        for (int kk = 0; kk < 4; kk++) {
            unsigned wv[4] = { pk[2 * kk][0], pk[2 * kk][1],
                               pk[2 * kk + 1][0], pk[2 * kk + 1][1] };
            bf16x8 bp; __builtin_memcpy(&bp, wv, 16);
#pragma unroll
            for (int jd = 0; jd < 4; jd++) {
                const u16* vb = Vs + (jd * 16 + l16) * 136 + kk * 32 + quad * 4;
                u16 va[8];
                *(u16x4*)(va)     = *(const u16x4*)(vb);
                *(u16x4*)(va + 4) = *(const u16x4*)(vb + 16);
                bf16x8 av; __builtin_memcpy(&av, va, 16);
                oacc[jd] = __builtin_amdgcn_mfma_f32_16x16x32_bf16(av, bp, oacc[jd], 0, 0, 0);
            }
        }

        if (more) {
            __syncthreads();    // all waves done reading current Ks/Vs
#pragma unroll
            for (int i = 0; i < 4; i++)
                *(u16x8*)(Ks + (i * 32 + krow) * 72 + kcol) = KR[i];
#pragma unroll
            for (int i = 0; i < 4; i++)
                *(u16x8*)(Vs + vrow * 136 + i * 32 + vcol) = VR[i];
            __syncthreads();
        }
    }

    // O^T element (d = jd*16 + quad*4 + r, q = l16): 4 consecutive cols/lane
    float linv = 1.f / l_st;
    long obase = ((long)b * LTOK + qrow) * DDIM + h * 64;
#pragma unroll
    for (int jd = 0; jd < 4; jd++) {
        u16x4 ov;
#pragma unroll
        for (int r = 0; r < 4; r++) ov[r] = f2bf(oacc[jd][r] * linv);
        *(u16x4*)(O + obase + jd * 16 + quad * 4) = ov;
    }
}

// out = LayerNorm(a + b) * g + beta.  a: bf16.  b: bf16 unless b32 (fp32).
// Output: bf16 (o) unless of != nullptr (fp32).  Row length 1024.
__global__ __launch_bounds__(256) void add_ln_kernel(
    const u16* __restrict__ a, const u16* __restrict__ b,
    const float* __restrict__ b32,
    const float* __restrict__ g, const float* __restrict__ bt,
    u16* __restrict__ o, float* __restrict__ of)
{
    long row = blockIdx.x;
    int tid = threadIdx.x;
    __shared__ float red[4];
    const u16* ar = a + row * DDIM;
    float xv[4]; float s = 0.f;
#pragma unroll
    for (int i = 0; i < 4; i++) {
        int c = tid + 256 * i;
        float sum = bf2f(ar[c]) + (b32 ? b32[row * DDIM + c] : bf2f(b[row * DDIM + c]));
        xv[i] = fminf(fmaxf(sum, -1.0e18f), 1.0e18f);
        s += xv[i];
    }
#pragma unroll
    for (int ofs = 32; ofs >= 1; ofs >>= 1) s += __shfl_xor(s, ofs);
    int wave = tid >> 6, lane = tid & 63;
    if (lane == 0) red[wave] = s;
    __syncthreads();
    float mu = (red[0] + red[1] + red[2] + red[3]) * (1.f / 1024.f);
    __syncthreads();
    float v = 0.f;
#pragma unroll
    for (int i = 0; i < 4; i++) { float d = xv[i] - mu; v += d * d; }
#pragma unroll
    for (int ofs = 32; ofs >= 1; ofs >>= 1) v += __shfl_xor(v, ofs);
    if (lane == 0) red[wave] = v;
    __syncthreads();
    float var = (red[0] + red[1] + red[2] + red[3]) * (1.f / 1024.f);
    float inv = rsqrtf(var + 1e-6f);
#pragma unroll
    for (int i = 0; i < 4; i++) {
        int c = tid + 256 * i;
        float r = (xv[i] - mu) * inv * g[c] + bt[c];
        if (of) of[row * DDIM + c] = r;
        else    o [row * DDIM + c] = f2bf(r);
    }
}

// fp32 -> bf16 conversion, 8 elements/thread, two tensors in one launch.
__global__ __launch_bounds__(256) void cvt2_kernel(
    const float* __restrict__ s0, u16* __restrict__ d0,
    const float* __restrict__ s1, u16* __restrict__ d1)
{
    const float* src = blockIdx.y ? s1 : s0;
    u16* dst = blockIdx.y ? d1 : d0;
    long i = ((long)blockIdx.x * 256 + threadIdx.x) * 8;
    u16x8 o;
#pragma unroll
    for (int j = 0; j < 8; j++) o[j] = f2bf(src[i + j]);
    *(u16x8*)(dst + i) = o;
}

// Transpose+cvt the 8 fp32 weight matrices (1024x1024): WT[n][k] = bf16(W[k][n])
__global__ __launch_bounds__(256) void wt_kernel(
    const float* w0, const float* w1, const float* w2, const float* w3,
    const float* w4, const float* w5, const float* w6, const float* w7,
    u16* __restrict__ wt)
{
    const float* srcs[8] = {w0, w1, w2, w3, w4, w5, w6, w7};
    const float* w = srcs[blockIdx.z];
    u16* o = wt + (long)blockIdx.z * DDIM * DDIM;
    __shared__ u16 t[32][33];
    int tx = threadIdx.x & 31, ty = threadIdx.x >> 5;
    int c0 = blockIdx.x << 5, r0 = blockIdx.y << 5;
#pragma unroll
    for (int i = 0; i < 4; i++)
        t[ty + 8 * i][tx] = f2bf(w[(long)(r0 + ty + 8 * i) * DDIM + c0 + tx]);
    __syncthreads();
#pragma unroll
    for (int i = 0; i < 4; i++)
        o[(long)(c0 + ty + 8 * i) * DDIM + r0 + tx] = t[tx][ty + 8 * i];
}

// Concatenate up to 3 bias vectors (1024 each) into one fp32 array.
__global__ __launch_bounds__(256) void biascat_kernel(
    const float* __restrict__ b0, const float* __restrict__ b1,
    const float* __restrict__ b2, float* __restrict__ dst)
{
    int i = blockIdx.x * 256 + threadIdx.x;
    const float* s = (i < 1024) ? b0 : (i < 2048) ? b1 : b2;
    dst[i] = s[i & 1023];
}

extern "C" void kernel_launch(void* const* d_in, const int* in_sizes, int n_in,
                              void* d_out, int out_size, void* d_ws, size_t ws_size,
                              hipStream_t stream)
{
    const float* x     = (const float*)d_in[0];
    const float* dmsk  = (const float*)d_in[1];
    const float* enc   = (const float*)d_in[2];
    const float* sa_wq = (const float*)d_in[3];  const float* sa_bq = (const float*)d_in[4];
    const float* sa_wk = (const float*)d_in[5];  const float* sa_bk = (const float*)d_in[6];
    const float* sa_wv = (const float*)d_in[7];  const float* sa_bv = (const float*)d_in[8];
    const float* n1_g  = (const float*)d_in[9];  const float* n1_b  = (const float*)d_in[10];
    const float* ca_wq = (const float*)d_in[11]; const float* ca_bq = (const float*)d_in[12];
    const float* ca_wk = (const float*)d_in[13]; const float* ca_bk = (const float*)d_in[14];
    const float* ca_wv = (const float*)d_in[15]; const float* ca_bv = (const float*)d_in[16];
    const float* n2_g  = (const float*)d_in[17]; const float* n2_b  = (const float*)d_in[18];
    const float* int_w = (const float*)d_in[19]; const float* int_b = (const float*)d_in[20];
    const float* out_w = (const float*)d_in[21]; const float* out_b = (const float*)d_in[22];
    const float* out_g = (const float*)d_in[23]; const float* out_bt= (const float*)d_in[24];

    float* outp = (float*)d_out;
    float* visp = outp + (long)NBATCH * LTOK * DDIM;   // attention_vis (fp32)

    // --- workspace: chunk over batches; 7 buffer units / batch + WT + bias ---
    const size_t WTB  = (size_t)8 * DDIM * DDIM * 2;            // 16 MiB
    const size_t BUF1 = (size_t)LTOK * DDIM * 2;                // 1 MiB / batch
    int cb = 16;
    while (cb > 1 && WTB + (size_t)cb * 7 * BUF1 + 32768 > ws_size)
        cb >>= 1;

    char* ws = (char*)d_ws;
    size_t off = 0;
    auto alloc = [&](size_t bytes) -> u16* {
        u16* p = (u16*)(ws + off);
        off += (bytes + 255) & ~(size_t)255;
        return p;
    };
    u16* Xb  = alloc((size_t)cb * BUF1);          // Xb -> h
    u16* Eb  = alloc((size_t)cb * BUF1);          // Eb -> h2
    u16* Q3  = alloc((size_t)cb * 3 * BUF1);      // q|k|(v unused) -> CQ | CKV
    u16* Vt  = alloc((size_t)cb * BUF1);          // per-head V^T -> I
    u16* Cx  = alloc((size_t)cb * BUF1);          // attn ctx -> G
    u16* WT  = alloc(WTB);
    float* biasQKV = (float*)alloc(3072 * sizeof(float));
    float* biasKV  = (float*)alloc(2048 * sizeof(float));
    // no memset needed: every region fully written before read.

    u16* Wsaq = WT + 0L * DDIM * DDIM;   // [Wsaq|Wsak|Wsav] contiguous => fused B
    u16* Wcaq = WT + 3L * DDIM * DDIM;
    u16* Wcak = WT + 4L * DDIM * DDIM;   // [Wcak|Wcav] contiguous => fused B
    u16* Wint = WT + 6L * DDIM * DDIM;
    u16* Wout = WT + 7L * DDIM * DDIM;

    // op builder: simple (Z=1) dense GEMM C[M x N] = A[M x K] @ B[N x K]^T
    auto mkop = [](const u16* A, int lda, const u16* B, int ldb,
                   u16* C, float* Cf, int ldc, int M, int N, int K,
                   const float* bias, float scale, int flags) -> GemmOp {
        GemmOp o{};
        o.A = A; o.B = B; o.C = C; o.Cf = Cf; o.bias = bias;
        o.VTp = nullptr; o.vtcol0 = 0;
        o.sA1 = 0; o.sA2 = 0; o.sB1 = 0; o.sB2 = 0; o.sC1 = 0; o.sC2 = 0;
        o.lda = lda; o.ldb = ldb; o.ldc = ldc; o.M = M; o.N = N; o.K = K;
        o.zdiv = 1; o.flags = flags; o.nblk = (M / 128) * (N / 128);
        o.scale = scale;
        return o;
    };

    auto launch = [&](int mode, GemmOp o1, GemmOp o2) {
        int nb = o1.nblk + o2.nblk;
        if (mode == 0)
            gemm_bt_kernel<0><<<dim3(nb), dim3(256), 0, stream>>>(o1, o2);
        else
            gemm_bt_kernel<1><<<dim3(nb), dim3(256), 0, stream>>>(o1, o2);
    };
    GemmOp nil{};   // nblk = 0

    const long SLD = (long)LTOK * DDIM;       // per-batch row-block stride
    const long SSC = (long)LTOK * LTOK;       // vis elems per batch

    // 0) weight transposes + bf16 cvt + bias packs (once per call)
    wt_kernel<<<dim3(32, 32, 8), dim3(256), 0, stream>>>(
        sa_wq, sa_wk, sa_wv, ca_wq, ca_wk, ca_wv, int_w, out_w, WT);
    biascat_kernel<<<dim3(12), dim3(256), 0, stream>>>(sa_bq, sa_bk, sa_bv, biasQKV);
    biascat_kernel<<<dim3(8),  dim3(256), 0, stream>>>(ca_bk, ca_bv, ca_bv, biasKV);

    for (int b0 = 0; b0 < NBATCH; b0 += cb) {
        const float* xc = x   + (long)b0 * SLD;
        const float* ec = enc + (long)b0 * SLD;
        const int M = cb * LTOK;
        const int Z = cb * NH;
        const int cvtg = (int)(((long)M * DDIM) / (256 * 8));

        u16* h   = Xb;                                   // LN1 out (Xb reuse)
        u16* CQ  = Q3;                                   // cross q
        u16* CKV = Q3 + (size_t)cb * LTOK * DDIM;        // cross k|v, ld 2048
        u16* I   = Vt;                                   // gelu FFN out (Vt reuse)
        u16* G   = Cx;                                   // out proj (Cx reuse)
        u16* h2  = Eb;                                   // LN2 out (Eb reuse)

        // a) fp32 -> bf16 activation copies (both tensors, one launch)
        cvt2_kernel<<<dim3(cvtg, 2), dim3(256), 0, stream>>>(xc, Xb, ec, Eb);

        // 1) fused self-attn q|k|v projection: N=3072 (1536 blocks, MODE0
        //    control).  V-third written transposed straight to Vt.
        {
            GemmOp o = mkop(Xb, DDIM, Wsaq, DDIM, Q3, nullptr, 3 * DDIM,
                            M, 3 * DDIM, DDIM, biasQKV, 1.f, 0);
            o.VTp = Vt; o.vtcol0 = 2 * DDIM;
            launch(0, o, nil);
        }

        // 2) self-attention (flash, causal+padding), ctx -> Cx
        flash_kernel<<<dim3(Z, 8), dim3(256), 0, stream>>>(
            Q3, Q3 + DDIM, Vt, Cx, dmsk + (long)b0 * LTOK, 1, 3 * DDIM, 3 * DDIM);

        // 3) h = LN(ctx + x_fp32) -> h (Xb reuse)
        add_ln_kernel<<<dim3(M), dim3(256), 0, stream>>>(
            Cx, nullptr, xc, n1_g, n1_b, h, nullptr);

        // 4) MERGED cq | cross-k|v: 1536 blocks, MODE1 challenger (A/B vs
        //    step-1's MODE0).  cv-third written transposed straight to Vt.
        {
            GemmOp okv = mkop(Eb, DDIM, Wcak, DDIM, CKV, nullptr, 2 * DDIM,
                              M, 2 * DDIM, DDIM, biasKV, 1.f, 0);
            okv.VTp = Vt; okv.vtcol0 = DDIM;
            launch(1, mkop(h, DDIM, Wcaq, DDIM, CQ, nullptr, DDIM,
                           M, DDIM, DDIM, ca_bq, 1.f, 0), okv);
        }

        // 5) cross-attention (flash, no mask): ctx -> Cx
        flash_kernel<<<dim3(Z, 8), dim3(256), 0, stream>>>(
            CQ, CKV, Vt, Cx, nullptr, 0, DDIM, 2 * DDIM);

        // 6) h2 = LN(h + cactx) -> h2 (Eb reuse)
        add_ln_kernel<<<dim3(M), dim3(256), 0, stream>>>(
            h, Cx, nullptr, n2_g, n2_b, h2, nullptr);

        // 7) MERGED vis | int: 256 + 512 = 768 blocks -> MODE1 (3/CU).
        GemmOp ovis{};
        ovis.A = CQ;  ovis.lda = DDIM;     ovis.sA1 = SLD;               ovis.sA2 = 0;
        ovis.B = CKV; ovis.ldb = 2 * DDIM; ovis.sB1 = (long)LTOK * 2 * DDIM; ovis.sB2 = 0;
        ovis.C = nullptr; ovis.Cf = visp + (long)b0 * SSC;
        ovis.VTp = nullptr; ovis.vtcol0 = 0;
        ovis.ldc = LTOK; ovis.sC1 = SSC; ovis.sC2 = 0;
        ovis.M = LTOK; ovis.N = LTOK; ovis.K = DDIM; ovis.zdiv = 1;
        ovis.bias = nullptr; ovis.scale = 1.f / 128.f; ovis.flags = 0;
        ovis.nblk = (LTOK / 128) * (LTOK / 128) * cb;     // 16 * cb
        launch(1, ovis,
               mkop(h2, DDIM, Wint, DDIM, I, nullptr, DDIM,
                    M, DDIM, DDIM, int_b, 1.f, 1));

        // 8) G = inter @ out_w + out_b -> G (Cx reuse; LN2 consumed Cx)
        launch(1, mkop(I, DDIM, Wout, DDIM, G, nullptr, DDIM,
                       M, DDIM, DDIM, out_b, 1.f, 0), nil);

        // 9) out = LN(G + inter) -> fp32 d_out
        add_ln_kernel<<<dim3(M), dim3(256), 0, stream>>>(
            G, I, nullptr, out_g, out_bt, nullptr, outp + (long)b0 * SLD);
    }
}

// Round 8
// 533.373 us; speedup vs baseline: 1.0992x; 1.0289x over previous
//
#include <hip/hip_runtime.h>
#include <hip/hip_bf16.h>
#include <math.h>

// Problem constants
#define DDIM 1024
#define NH   16
#define LTOK 512
#define NBATCH 16

typedef unsigned short u16;
typedef unsigned short u16x8 __attribute__((ext_vector_type(8)));
typedef unsigned short u16x4 __attribute__((ext_vector_type(4)));
typedef __bf16 bf16x8 __attribute__((ext_vector_type(8)));
typedef float f32x4 __attribute__((ext_vector_type(4)));

typedef __attribute__((address_space(1))) void as1_void;
typedef __attribute__((address_space(3))) void as3_void;

__device__ __forceinline__ void llds16(const u16* g, u16* l) {
    // async 16B global->LDS DMA; LDS dest = wave-uniform base + lane*16B
    __builtin_amdgcn_global_load_lds((as1_void*)g, (as3_void*)l, 16, 0, 0);
}

__device__ __forceinline__ float bf2f(u16 u) {
    unsigned v = ((unsigned)u) << 16;
    float f; __builtin_memcpy(&f, &v, 4); return f;
}
__device__ __forceinline__ u16 f2bf(float f) {
    unsigned u; __builtin_memcpy(&u, &f, 4);
    u += 0x7fffu + ((u >> 16) & 1u);   // RNE
    return (u16)(u >> 16);
}

// One GEMM operand set:  C = act(scale*(A@B^T)+bias).  M,N multiples of 128,
// K multiple of 32 (all call sites comply).  nblk = (M/128)*(N/128)*Z.
// If VTp != nullptr, output columns >= vtcol0 are per-head V projections and
// are written TRANSPOSED to VTp[((row/512)*NH + h)*64 + dd][row%512] instead
// of C (nothing reads V in row layout; flash consumes VT only).
struct GemmOp {
    const u16* A; const u16* B; u16* C; float* Cf; const float* bias;
    u16* VTp;
    long sA1, sA2, sB1, sB2, sC1, sC2;
    int lda, ldb, ldc, M, N, K, zdiv, flags, nblk, vtcol0;
    float scale;
};

// ---------------------------------------------------------------------------
// Dual-op MFMA GEMM.  1-D grid; blocks [0, o1.nblk) run o1, the rest run o2
// (uniform per-block branch) -- merging independent GEMMs raises blocks/CU.
// MODE 0: single-buffer, 2 barriers/K-step (16KB LDS).
// MODE 1: 2-buffer double-buffer, 1 barrier/K-step (32KB) -- next tile's DMA
//         in flight across the whole compute phase.  [r7 A/B: MODE1 >= MODE0
//         at 6 blocks/CU with the C^T epilogue -> all launches use MODE1.]
// Epilogue computes C^T fragments via mfma operand swap -> each lane holds 4
// consecutive columns -> vectorized u16x4/f32x4 stores; V-column tiles are
// redirected to the per-head transposed VT layout (kills vtrans kernels).
// XCD swizzle (T1) when tilesM%8==0.
// ---------------------------------------------------------------------------
template<int MODE>
__global__ __launch_bounds__(256) void gemm_bt_kernel(GemmOp o1, GemmOp o2)
{
    constexpr int NB   = (MODE == 0) ? 1 : 2;
    constexpr int BUFE = 128 * 32;
    __shared__ __align__(16) u16 As[NB * BUFE];
    __shared__ __align__(16) u16 Bs[NB * BUFE];

    const bool second = (int)blockIdx.x >= o1.nblk;
    const GemmOp& o = second ? o2 : o1;
    int bidx = blockIdx.x - (second ? o1.nblk : 0);

    const int tilesN = o.N >> 7;
    const int tilesM = o.M >> 7;
    const int tiles  = tilesM * tilesN;
    const int z = bidx / tiles;
    const int t = bidx - z * tiles;
    const int zb = z / o.zdiv, zh = z - zb * o.zdiv;

    int tm, tn;
    if ((tilesM & 7) == 0) {
        // bijective XCD-grouping swizzle: tm % 8 == linear idx % 8
        const int xcd = t & 7, idx = t >> 3;
        const int mg  = tilesM >> 3;
        tm = ((idx % mg) << 3) | xcd;
        tn = idx / mg;
    } else {
        tm = t / tilesN;
        tn = t - tm * tilesN;
    }
    const int m0 = tm << 7, n0 = tn << 7;

    const u16* Ab = o.A + (long)zb * o.sA1 + (long)zh * o.sA2;
    const u16* Bb = o.B + (long)zb * o.sB1 + (long)zh * o.sB2;
    u16*   Cb  = o.C  ? o.C  + (long)zb * o.sC1 + (long)zh * o.sC2 : nullptr;
    float* Cfb = o.Cf ? o.Cf + (long)zb * o.sC1 + (long)zh * o.sC2 : nullptr;

    const int tid  = threadIdx.x;
    const int lane = tid & 63;
    const int wave = tid >> 6;
    const int wm = (wave & 1) << 6, wn = (wave >> 1) << 6;
    const int quad = lane >> 4, l16 = lane & 15;

    f32x4 acc[4][4];
#pragma unroll
    for (int i = 0; i < 4; i++)
#pragma unroll
        for (int j = 0; j < 4; j++) acc[i][j] = (f32x4){0.f, 0.f, 0.f, 0.f};

    const int lrA = (wave << 5) + (lane >> 2);
    const int lc  = (lane & 3) << 3;
    const u16* gA0 = Ab + (long)(m0 + lrA) * o.lda + lc;
    const u16* gA1 = Ab + (long)(m0 + lrA + 16) * o.lda + lc;
    const u16* gB0 = Bb + (long)(n0 + lrA) * o.ldb + lc;
    const u16* gB1 = Bb + (long)(n0 + lrA + 16) * o.ldb + lc;
    u16* lA0 = As + ((wave << 5) +  0) * 32;
    u16* lA1 = As + ((wave << 5) + 16) * 32;
    u16* lB0 = Bs + ((wave << 5) +  0) * 32;
    u16* lB1 = Bs + ((wave << 5) + 16) * 32;

    auto STAGE = [&](int bi, int k0) {
        llds16(gA0 + k0, lA0 + bi * BUFE);
        llds16(gA1 + k0, lA1 + bi * BUFE);
        llds16(gB0 + k0, lB0 + bi * BUFE);
        llds16(gB1 + k0, lB1 + bi * BUFE);
    };
    auto COMPUTE = [&](int bi) {
        const u16* Ac = As + bi * BUFE;
        const u16* Bc = Bs + bi * BUFE;
        bf16x8 af[4], bfr[4];
#pragma unroll
        for (int t2 = 0; t2 < 4; t2++)
            af[t2] = *(const bf16x8*)(Ac + (wm + t2 * 16 + l16) * 32 + quad * 8);
#pragma unroll
        for (int t2 = 0; t2 < 4; t2++)
            bfr[t2] = *(const bf16x8*)(Bc + (wn + t2 * 16 + l16) * 32 + quad * 8);
        // operand-swapped: acc[i][j] holds C^T fragment ->
        //   acc[i][j][r] = C[m0+wm+i*16+l16][n0+wn+j*16+quad*4+r]
#pragma unroll
        for (int i = 0; i < 4; i++)
#pragma unroll
            for (int j = 0; j < 4; j++)
                acc[i][j] = __builtin_amdgcn_mfma_f32_16x16x32_bf16(
                    bfr[j], af[i], acc[i][j], 0, 0, 0);
    };

    const int K = o.K;
    if (MODE == 0) {
        for (int k0 = 0; k0 < K; k0 += 32) {
            __syncthreads();
            STAGE(0, k0);
            __syncthreads();
            COMPUTE(0);
        }
    } else {
        STAGE(0, 0);
        __syncthreads();
        int cur = 0;
        for (int k0 = 0; k0 < K; k0 += 32) {
            const int nxt = cur ^ 1;
            if (k0 + 32 < K) STAGE(nxt, k0 + 32);
            COMPUTE(cur);
            __syncthreads();
            cur = nxt;
        }
    }

    // C^T epilogue: lane writes 4 consecutive cols per (i,j).
    // V-column tiles (col >= vtcol0, tile-uniform) go transposed to VT.
#pragma unroll
    for (int i = 0; i < 4; i++) {
        const long row = m0 + wm + i * 16 + l16;
#pragma unroll
        for (int j = 0; j < 4; j++) {
            const int col = n0 + wn + j * 16 + quad * 4;
            f32x4 bv = o.bias ? *(const f32x4*)(o.bias + col)
                              : (f32x4){0.f, 0.f, 0.f, 0.f};
            f32x4 v4;
#pragma unroll
            for (int r = 0; r < 4; r++) {
                float v = acc[i][j][r] * o.scale + bv[r];
                if (o.flags & 1)
                    v = 0.5f * v * (1.f + erff(v * 0.70710678118654752f));
                v4[r] = v;
            }
            if (o.VTp && col >= o.vtcol0) {
                const int dv  = col - o.vtcol0;          // head h = dv>>6
                const long bh = (row >> 9) * NH + (dv >> 6);
                const int tok = (int)(row & (LTOK - 1));
                u16* vp = o.VTp + (bh * 64 + (dv & 63)) * LTOK + tok;
#pragma unroll
                for (int r = 0; r < 4; r++)
                    vp[(long)r * LTOK] = f2bf(v4[r]);
            } else if (Cfb) {
                *(f32x4*)(Cfb + row * o.ldc + col) = v4;
            } else {
                u16x4 ov;
#pragma unroll
                for (int r = 0; r < 4; r++) ov[r] = f2bf(v4[r]);
                *(u16x4*)(Cb + row * o.ldc + col) = ov;
            }
        }
    }
}

// ---------------------------------------------------------------------------
// Flash attention: O = softmax(scale*Q K^T + mask) V, head dim 64, L = 512.
//   Q: (b, 512, ldq) bf16, head h at cols h*64;  K: (b, 512, ldk) bf16
//   VT: (bh, 64, 512) bf16 (per-head V^T);  O: (b, 512, 1024) bf16
// grid (bh=cb*16, qt=4): 128 q-rows per block; bh FAST so the qt-blocks of
// one head land on the SAME XCD -> K/VT L2-served after first fetch.
// Block: 4 waves; EACH WAVE OWNS 32 q-rows (2 sub-tiles of 16) so every
// K-fragment LDS read feeds 2 S-MFMAs and every V-fragment read feeds 2
// PV-MFMAs -- LDS reads / staging / barriers per unit work are HALVED vs the
// 16-row version (the kernel was LDS-pipe-bound at MfmaUtil 13%).
// Swapped-operand S^T = mfma(K,Q); softmax in-register (exp2, cvt_pk);
// zero-shuffle PV via key-permutation sigma; T14 async-STAGE.
// ~190 VGPR -> __launch_bounds__(256,2).
// ---------------------------------------------------------------------------
__global__ __launch_bounds__(256, 2) void flash_kernel(
    const u16* __restrict__ Q, const u16* __restrict__ K,
    const u16* __restrict__ VT, u16* __restrict__ O,
    const float* __restrict__ mask, int causal, int ldq, int ldk)
{
    __shared__ __align__(16) u16 Ks[128 * 72];    // keys x dims, pad 64->72
    __shared__ __align__(16) u16 Vs[64 * 136];    // dims x keys, pad 128->136
    const int tid  = threadIdx.x;
    const int wave = tid >> 6, lane = tid & 63;
    const int quad = lane >> 4, l16 = lane & 15;
    const int bh = blockIdx.x, qt = blockIdx.y, b = bh >> 4, h = bh & 15;
    const int qbase = qt * 128 + wave * 32;
    const int qrow0 = qbase + l16;            // sub-tile 0 q row
    const int qrow1 = qbase + 16 + l16;       // sub-tile 1 q row

    const u16* qp0 = Q + ((long)b * LTOK + qrow0) * ldq + h * 64 + quad * 8;
    const u16* qp1 = qp0 + (long)16 * ldq;
    bf16x8 aq00 = *(const bf16x8*)(qp0);
    bf16x8 aq01 = *(const bf16x8*)(qp0 + 32);
    bf16x8 aq10 = *(const bf16x8*)(qp1);
    bf16x8 aq11 = *(const bf16x8*)(qp1 + 32);

    f32x4 oacc0[4], oacc1[4];
#pragma unroll
    for (int jd = 0; jd < 4; jd++) {
        oacc0[jd] = (f32x4){0.f, 0.f, 0.f, 0.f};
        oacc1[jd] = (f32x4){0.f, 0.f, 0.f, 0.f};
    }
    float m0_ = -3.0e38f, m1_ = -3.0e38f;    // running max, log2 domain
    float l0_ = 0.f, l1_ = 0.f;              // running denom

    const int krow = tid >> 3,       kcol = (tid & 7) << 3;   // K: 32 rows/issue
    const int vrow = tid >> 2,       vcol = (tid & 3) << 3;   // VT: 64 rows
    const u16* gK = K + ((long)b * LTOK + krow) * ldk + h * 64 + kcol;
    const u16* gV = VT + ((long)bh * 64 + vrow) * LTOK + vcol;

    const float C1    = 0.125f * 1.44269504088896340736f;   // scale*log2(e)
    const float NEGL2 = -10000.0f * 1.44269504088896340736f;

    const int nkt = causal ? (qt + 1) : (LTOK >> 7);

    // ---- prologue: stage tile 0 ----
    u16x8 KR[4], VR[4];
#pragma unroll
    for (int i = 0; i < 4; i++) KR[i] = *(const u16x8*)(gK + (long)(i * 32) * ldk);
#pragma unroll
    for (int i = 0; i < 4; i++) VR[i] = *(const u16x8*)(gV + i * 32);
#pragma unroll
    for (int i = 0; i < 4; i++)
        *(u16x8*)(Ks + (i * 32 + krow) * 72 + kcol) = KR[i];
#pragma unroll
    for (int i = 0; i < 4; i++)
        *(u16x8*)(Vs + vrow * 136 + i * 32 + vcol) = VR[i];
    __syncthreads();

    for (int kt = 0; kt < nkt; kt++) {
        const int k0 = kt << 7;
        const bool more = (kt + 1 < nkt);     // block-uniform

        // T14: issue next tile's global loads now; write to LDS after compute
        if (more) {
            const int kn = k0 + 128;
#pragma unroll
            for (int i = 0; i < 4; i++)
                KR[i] = *(const u16x8*)(gK + (long)(kn + i * 32) * ldk);
#pragma unroll
            for (int i = 0; i < 4; i++)
                VR[i] = *(const u16x8*)(gV + kn + i * 32);
        }

        // S^T = K Q^T for both q-sub-tiles; each bk pair feeds 2 MFMAs.
        // C-layout: col = l16 = q, row = key = j*16 + quad*4 + r
        f32x4 s0[8], s1[8];
#pragma unroll
        for (int j = 0; j < 8; j++) {
            bf16x8 bk0 = *(const bf16x8*)(Ks + (j * 16 + l16) * 72 + quad * 8);
            bf16x8 bk1 = *(const bf16x8*)(Ks + (j * 16 + l16) * 72 + 32 + quad * 8);
            f32x4 z0 = (f32x4){0.f, 0.f, 0.f, 0.f};
            z0 = __builtin_amdgcn_mfma_f32_16x16x32_bf16(bk0, aq00, z0, 0, 0, 0);
            s0[j] = __builtin_amdgcn_mfma_f32_16x16x32_bf16(bk1, aq01, z0, 0, 0, 0);
            f32x4 z1 = (f32x4){0.f, 0.f, 0.f, 0.f};
            z1 = __builtin_amdgcn_mfma_f32_16x16x32_bf16(bk0, aq10, z1, 0, 0, 0);
            s1[j] = __builtin_amdgcn_mfma_f32_16x16x32_bf16(bk1, aq11, z1, 0, 0, 0);
        }

        // scale (+mask) in log2 domain; per-lane tile max (both sub-tiles)
        float ta0 = -3.0e38f, ta1 = -3.0e38f, ta2 = -3.0e38f, ta3 = -3.0e38f;
        float tb0 = -3.0e38f, tb1 = -3.0e38f, tb2 = -3.0e38f, tb3 = -3.0e38f;
#pragma unroll
        for (int j = 0; j < 8; j++) {
            if (causal) {
                f32x4 m4 = *(const f32x4*)(mask + (long)b * LTOK + k0 + j * 16 + quad * 4);
#pragma unroll
                for (int r = 0; r < 4; r++) {
                    int key = k0 + j * 16 + quad * 4 + r;
                    float adm = fmaf(m4[r], -NEGL2, NEGL2);
                    s0[j][r] = fmaf(s0[j][r], C1, (key <= qrow0) ? adm : NEGL2);
                    s1[j][r] = fmaf(s1[j][r], C1, (key <= qrow1) ? adm : NEGL2);
                }
            } else {
#pragma unroll
                for (int r = 0; r < 4; r++) { s0[j][r] *= C1; s1[j][r] *= C1; }
            }
            ta0 = fmaxf(ta0, s0[j][0]); ta1 = fmaxf(ta1, s0[j][1]);
            ta2 = fmaxf(ta2, s0[j][2]); ta3 = fmaxf(ta3, s0[j][3]);
            tb0 = fmaxf(tb0, s1[j][0]); tb1 = fmaxf(tb1, s1[j][1]);
            tb2 = fmaxf(tb2, s1[j][2]); tb3 = fmaxf(tb3, s1[j][3]);
        }
        float tmax0 = fmaxf(fmaxf(ta0, ta1), fmaxf(ta2, ta3));
        float tmax1 = fmaxf(fmaxf(tb0, tb1), fmaxf(tb2, tb3));
        tmax0 = fmaxf(tmax0, __shfl_xor(tmax0, 16));
        tmax0 = fmaxf(tmax0, __shfl_xor(tmax0, 32));
        tmax1 = fmaxf(tmax1, __shfl_xor(tmax1, 16));
        tmax1 = fmaxf(tmax1, __shfl_xor(tmax1, 32));

        float mn0 = fmaxf(m0_, tmax0);
        float mn1 = fmaxf(m1_, tmax1);
        float al0 = __builtin_amdgcn_exp2f(m0_ - mn0);
        float al1 = __builtin_amdgcn_exp2f(m1_ - mn1);
        m0_ = mn0; m1_ = mn1;

        // P = exp2(S - m); pack to bf16 pairs in-register (s dies into pk)
        unsigned pk0[8][2], pk1[8][2];
        float ra0 = 0.f, ra1 = 0.f, ra2 = 0.f, ra3 = 0.f;
#pragma unroll
        for (int j = 0; j < 8; j++) {
            float p0 = __builtin_amdgcn_exp2f(s0[j][0] - mn0);
            float p1 = __builtin_amdgcn_exp2f(s0[j][1] - mn0);
            float p2 = __builtin_amdgcn_exp2f(s0[j][2] - mn0);
            float p3 = __builtin_amdgcn_exp2f(s0[j][3] - mn0);
            ra0 += p0; ra1 += p1; ra2 += p2; ra3 += p3;
            asm("v_cvt_pk_bf16_f32 %0, %1, %2" : "=v"(pk0[j][0]) : "v"(p0), "v"(p1));
            asm("v_cvt_pk_bf16_f32 %0, %1, %2" : "=v"(pk0[j][1]) : "v"(p2), "v"(p3));
        }
        float rsum0 = (ra0 + ra1) + (ra2 + ra3);
        float rb0 = 0.f, rb1 = 0.f, rb2 = 0.f, rb3 = 0.f;
#pragma unroll
        for (int j = 0; j < 8; j++) {
            float p0 = __builtin_amdgcn_exp2f(s1[j][0] - mn1);
            float p1 = __builtin_amdgcn_exp2f(s1[j][1] - mn1);
            float p2 = __builtin_amdgcn_exp2f(s1[j][2] - mn1);
            float p3 = __builtin_amdgcn_exp2f(s1[j][3] - mn1);
            rb0 += p0; rb1 += p1; rb2 += p2; rb3 += p3;
            asm("v_cvt_pk_bf16_f32 %0, %1, %2" : "=v"(pk1[j][0]) : "v"(p0), "v"(p1));
            asm("v_cvt_pk_bf16_f32 %0, %1, %2" : "=v"(pk1[j][1]) : "v"(p2), "v"(p3));
        }
        float rsum1 = (rb0 + rb1) + (rb2 + rb3);
        rsum0 += __shfl_xor(rsum0, 16);
        rsum0 += __shfl_xor(rsum0, 32);
        rsum1 += __shfl_xor(rsum1, 16);
        rsum1 += __shfl_xor(rsum1, 32);
        l0_ = l0_ * al0 + rsum0;
        l1_ = l1_ * al1 + rsum1;

#pragma unroll
        for (int jd = 0; jd < 4; jd++) { oacc0[jd] *= al0; oacc1[jd] *= al1; }

        // O^T += V^T P^T under key-permutation sigma (zero shuffles);
        // each av read feeds BOTH sub-tiles' PV MFMAs.
#pragma unroll
        for (int kk = 0; kk < 4; kk++) {
            unsigned wv0[4] = { pk0[2 * kk][0], pk0[2 * kk][1],
                                pk0[2 * kk + 1][0], pk0[2 * kk + 1][1] };
            unsigned wv1[4] = { pk1[2 * kk][0], pk1[2 * kk][1],
                                pk1[2 * kk + 1][0], pk1[2 * kk + 1][1] };
            bf16x8 bp0; __builtin_memcpy(&bp0, wv0, 16);
            bf16x8 bp1; __builtin_memcpy(&bp1, wv1, 16);
#pragma unroll
            for (int jd = 0; jd < 4; jd++) {
                const u16* vb = Vs + (jd * 16 + l16) * 136 + kk * 32 + quad * 4;
                u16 va[8];
                *(u16x4*)(va)     = *(const u16x4*)(vb);
                *(u16x4*)(va + 4) = *(const u16x4*)(vb + 16);
                bf16x8 av; __builtin_memcpy(&av, va, 16);
                oacc0[jd] = __builtin_amdgcn_mfma_f32_16x16x32_bf16(av, bp0, oacc0[jd], 0, 0, 0);
                oacc1[jd] = __builtin_amdgcn_mfma_f32_16x16x32_bf16(av, bp1, oacc1[jd], 0, 0, 0);
            }
        }

        if (more) {
            __syncthreads();    // all waves done reading current Ks/Vs
#pragma unroll
            for (int i = 0; i < 4; i++)
                *(u16x8*)(Ks + (i * 32 + krow) * 72 + kcol) = KR[i];
#pragma unroll
            for (int i = 0; i < 4; i++)
                *(u16x8*)(Vs + vrow * 136 + i * 32 + vcol) = VR[i];
            __syncthreads();
        }
    }

    // O^T element (d = jd*16 + quad*4 + r, q = l16): 4 consecutive cols/lane
    float li0 = 1.f / l0_;
    float li1 = 1.f / l1_;
    long obase0 = ((long)b * LTOK + qrow0) * DDIM + h * 64;
    long obase1 = obase0 + (long)16 * DDIM;
#pragma unroll
    for (int jd = 0; jd < 4; jd++) {
        u16x4 ov0, ov1;
#pragma unroll
        for (int r = 0; r < 4; r++) {
            ov0[r] = f2bf(oacc0[jd][r] * li0);
            ov1[r] = f2bf(oacc1[jd][r] * li1);
        }
        *(u16x4*)(O + obase0 + jd * 16 + quad * 4) = ov0;
        *(u16x4*)(O + obase1 + jd * 16 + quad * 4) = ov1;
    }
}

// out = LayerNorm(a + b) * g + beta.  a: bf16.  b: bf16 unless b32 (fp32).
// Output: bf16 (o) unless of != nullptr (fp32).  Row length 1024.
__global__ __launch_bounds__(256) void add_ln_kernel(
    const u16* __restrict__ a, const u16* __restrict__ b,
    const float* __restrict__ b32,
    const float* __restrict__ g, const float* __restrict__ bt,
    u16* __restrict__ o, float* __restrict__ of)
{
    long row = blockIdx.x;
    int tid = threadIdx.x;
    __shared__ float red[4];
    const u16* ar = a + row * DDIM;
    float xv[4]; float s = 0.f;
#pragma unroll
    for (int i = 0; i < 4; i++) {
        int c = tid + 256 * i;
        float sum = bf2f(ar[c]) + (b32 ? b32[row * DDIM + c] : bf2f(b[row * DDIM + c]));
        xv[i] = fminf(fmaxf(sum, -1.0e18f), 1.0e18f);
        s += xv[i];
    }
#pragma unroll
    for (int ofs = 32; ofs >= 1; ofs >>= 1) s += __shfl_xor(s, ofs);
    int wave = tid >> 6, lane = tid & 63;
    if (lane == 0) red[wave] = s;
    __syncthreads();
    float mu = (red[0] + red[1] + red[2] + red[3]) * (1.f / 1024.f);
    __syncthreads();
    float v = 0.f;
#pragma unroll
    for (int i = 0; i < 4; i++) { float d = xv[i] - mu; v += d * d; }
#pragma unroll
    for (int ofs = 32; ofs >= 1; ofs >>= 1) v += __shfl_xor(v, ofs);
    if (lane == 0) red[wave] = v;
    __syncthreads();
    float var = (red[0] + red[1] + red[2] + red[3]) * (1.f / 1024.f);
    float inv = rsqrtf(var + 1e-6f);
#pragma unroll
    for (int i = 0; i < 4; i++) {
        int c = tid + 256 * i;
        float r = (xv[i] - mu) * inv * g[c] + bt[c];
        if (of) of[row * DDIM + c] = r;
        else    o [row * DDIM + c] = f2bf(r);
    }
}

// fp32 -> bf16 conversion, 8 elements/thread, two tensors in one launch.
__global__ __launch_bounds__(256) void cvt2_kernel(
    const float* __restrict__ s0, u16* __restrict__ d0,
    const float* __restrict__ s1, u16* __restrict__ d1)
{
    const float* src = blockIdx.y ? s1 : s0;
    u16* dst = blockIdx.y ? d1 : d0;
    long i = ((long)blockIdx.x * 256 + threadIdx.x) * 8;
    u16x8 o;
#pragma unroll
    for (int j = 0; j < 8; j++) o[j] = f2bf(src[i + j]);
    *(u16x8*)(dst + i) = o;
}

// Transpose+cvt the 8 fp32 weight matrices (1024x1024): WT[n][k] = bf16(W[k][n])
__global__ __launch_bounds__(256) void wt_kernel(
    const float* w0, const float* w1, const float* w2, const float* w3,
    const float* w4, const float* w5, const float* w6, const float* w7,
    u16* __restrict__ wt)
{
    const float* srcs[8] = {w0, w1, w2, w3, w4, w5, w6, w7};
    const float* w = srcs[blockIdx.z];
    u16* o = wt + (long)blockIdx.z * DDIM * DDIM;
    __shared__ u16 t[32][33];
    int tx = threadIdx.x & 31, ty = threadIdx.x >> 5;
    int c0 = blockIdx.x << 5, r0 = blockIdx.y << 5;
#pragma unroll
    for (int i = 0; i < 4; i++)
        t[ty + 8 * i][tx] = f2bf(w[(long)(r0 + ty + 8 * i) * DDIM + c0 + tx]);
    __syncthreads();
#pragma unroll
    for (int i = 0; i < 4; i++)
        o[(long)(c0 + ty + 8 * i) * DDIM + r0 + tx] = t[tx][ty + 8 * i];
}

// Concatenate up to 3 bias vectors (1024 each) into one fp32 array.
__global__ __launch_bounds__(256) void biascat_kernel(
    const float* __restrict__ b0, const float* __restrict__ b1,
    const float* __restrict__ b2, float* __restrict__ dst)
{
    int i = blockIdx.x * 256 + threadIdx.x;
    const float* s = (i < 1024) ? b0 : (i < 2048) ? b1 : b2;
    dst[i] = s[i & 1023];
}

extern "C" void kernel_launch(void* const* d_in, const int* in_sizes, int n_in,
                              void* d_out, int out_size, void* d_ws, size_t ws_size,
                              hipStream_t stream)
{
    const float* x     = (const float*)d_in[0];
    const float* dmsk  = (const float*)d_in[1];
    const float* enc   = (const float*)d_in[2];
    const float* sa_wq = (const float*)d_in[3];  const float* sa_bq = (const float*)d_in[4];
    const float* sa_wk = (const float*)d_in[5];  const float* sa_bk = (const float*)d_in[6];
    const float* sa_wv = (const float*)d_in[7];  const float* sa_bv = (const float*)d_in[8];
    const float* n1_g  = (const float*)d_in[9];  const float* n1_b  = (const float*)d_in[10];
    const float* ca_wq = (const float*)d_in[11]; const float* ca_bq = (const float*)d_in[12];
    const float* ca_wk = (const float*)d_in[13]; const float* ca_bk = (const float*)d_in[14];
    const float* ca_wv = (const float*)d_in[15]; const float* ca_bv = (const float*)d_in[16];
    const float* n2_g  = (const float*)d_in[17]; const float* n2_b  = (const float*)d_in[18];
    const float* int_w = (const float*)d_in[19]; const float* int_b = (const float*)d_in[20];
    const float* out_w = (const float*)d_in[21]; const float* out_b = (const float*)d_in[22];
    const float* out_g = (const float*)d_in[23]; const float* out_bt= (const float*)d_in[24];

    float* outp = (float*)d_out;
    float* visp = outp + (long)NBATCH * LTOK * DDIM;   // attention_vis (fp32)

    // --- workspace: chunk over batches; 7 buffer units / batch + WT + bias ---
    const size_t WTB  = (size_t)8 * DDIM * DDIM * 2;            // 16 MiB
    const size_t BUF1 = (size_t)LTOK * DDIM * 2;                // 1 MiB / batch
    int cb = 16;
    while (cb > 1 && WTB + (size_t)cb * 7 * BUF1 + 32768 > ws_size)
        cb >>= 1;

    char* ws = (char*)d_ws;
    size_t off = 0;
    auto alloc = [&](size_t bytes) -> u16* {
        u16* p = (u16*)(ws + off);
        off += (bytes + 255) & ~(size_t)255;
        return p;
    };
    u16* Xb  = alloc((size_t)cb * BUF1);          // Xb -> h
    u16* Eb  = alloc((size_t)cb * BUF1);          // Eb -> h2
    u16* Q3  = alloc((size_t)cb * 3 * BUF1);      // q|k|(v unused) -> CQ | CKV
    u16* Vt  = alloc((size_t)cb * BUF1);          // per-head V^T -> I
    u16* Cx  = alloc((size_t)cb * BUF1);          // attn ctx -> G
    u16* WT  = alloc(WTB);
    float* biasQKV = (float*)alloc(3072 * sizeof(float));
    float* biasKV  = (float*)alloc(2048 * sizeof(float));
    // no memset needed: every region fully written before read.

    u16* Wsaq = WT + 0L * DDIM * DDIM;   // [Wsaq|Wsak|Wsav] contiguous => fused B
    u16* Wcaq = WT + 3L * DDIM * DDIM;
    u16* Wcak = WT + 4L * DDIM * DDIM;   // [Wcak|Wcav] contiguous => fused B
    u16* Wint = WT + 6L * DDIM * DDIM;
    u16* Wout = WT + 7L * DDIM * DDIM;

    // op builder: simple (Z=1) dense GEMM C[M x N] = A[M x K] @ B[N x K]^T
    auto mkop = [](const u16* A, int lda, const u16* B, int ldb,
                   u16* C, float* Cf, int ldc, int M, int N, int K,
                   const float* bias, float scale, int flags) -> GemmOp {
        GemmOp o{};
        o.A = A; o.B = B; o.C = C; o.Cf = Cf; o.bias = bias;
        o.VTp = nullptr; o.vtcol0 = 0;
        o.sA1 = 0; o.sA2 = 0; o.sB1 = 0; o.sB2 = 0; o.sC1 = 0; o.sC2 = 0;
        o.lda = lda; o.ldb = ldb; o.ldc = ldc; o.M = M; o.N = N; o.K = K;
        o.zdiv = 1; o.flags = flags; o.nblk = (M / 128) * (N / 128);
        o.scale = scale;
        return o;
    };

    auto launch = [&](GemmOp o1, GemmOp o2) {
        int nb = o1.nblk + o2.nblk;
        gemm_bt_kernel<1><<<dim3(nb), dim3(256), 0, stream>>>(o1, o2);
    };
    GemmOp nil{};   // nblk = 0

    const long SLD = (long)LTOK * DDIM;       // per-batch row-block stride
    const long SSC = (long)LTOK * LTOK;       // vis elems per batch

    // 0) weight transposes + bf16 cvt + bias packs (once per call)
    wt_kernel<<<dim3(32, 32, 8), dim3(256), 0, stream>>>(
        sa_wq, sa_wk, sa_wv, ca_wq, ca_wk, ca_wv, int_w, out_w, WT);
    biascat_kernel<<<dim3(12), dim3(256), 0, stream>>>(sa_bq, sa_bk, sa_bv, biasQKV);
    biascat_kernel<<<dim3(8),  dim3(256), 0, stream>>>(ca_bk, ca_bv, ca_bv, biasKV);

    for (int b0 = 0; b0 < NBATCH; b0 += cb) {
        const float* xc = x   + (long)b0 * SLD;
        const float* ec = enc + (long)b0 * SLD;
        const int M = cb * LTOK;
        const int Z = cb * NH;
        const int cvtg = (int)(((long)M * DDIM) / (256 * 8));

        u16* h   = Xb;                                   // LN1 out (Xb reuse)
        u16* CQ  = Q3;                                   // cross q
        u16* CKV = Q3 + (size_t)cb * LTOK * DDIM;        // cross k|v, ld 2048
        u16* I   = Vt;                                   // gelu FFN out (Vt reuse)
        u16* G   = Cx;                                   // out proj (Cx reuse)
        u16* h2  = Eb;                                   // LN2 out (Eb reuse)

        // a) fp32 -> bf16 activation copies (both tensors, one launch)
        cvt2_kernel<<<dim3(cvtg, 2), dim3(256), 0, stream>>>(xc, Xb, ec, Eb);

        // 1) fused self-attn q|k|v projection: N=3072 (1536 blocks, MODE1).
        //    V-third written transposed straight to Vt.
        {
            GemmOp o = mkop(Xb, DDIM, Wsaq, DDIM, Q3, nullptr, 3 * DDIM,
                            M, 3 * DDIM, DDIM, biasQKV, 1.f, 0);
            o.VTp = Vt; o.vtcol0 = 2 * DDIM;
            launch(o, nil);
        }

        // 2) self-attention (flash, causal+padding), ctx -> Cx
        flash_kernel<<<dim3(Z, 4), dim3(256), 0, stream>>>(
            Q3, Q3 + DDIM, Vt, Cx, dmsk + (long)b0 * LTOK, 1, 3 * DDIM, 3 * DDIM);

        // 3) h = LN(ctx + x_fp32) -> h (Xb reuse)
        add_ln_kernel<<<dim3(M), dim3(256), 0, stream>>>(
            Cx, nullptr, xc, n1_g, n1_b, h, nullptr);

        // 4) MERGED cq | cross-k|v: 1536 blocks, MODE1.
        //    cv-third written transposed straight to Vt.
        {
            GemmOp okv = mkop(Eb, DDIM, Wcak, DDIM, CKV, nullptr, 2 * DDIM,
                              M, 2 * DDIM, DDIM, biasKV, 1.f, 0);
            okv.VTp = Vt; okv.vtcol0 = DDIM;
            launch(mkop(h, DDIM, Wcaq, DDIM, CQ, nullptr, DDIM,
                        M, DDIM, DDIM, ca_bq, 1.f, 0), okv);
        }

        // 5) cross-attention (flash, no mask): ctx -> Cx
        flash_kernel<<<dim3(Z, 4), dim3(256), 0, stream>>>(
            CQ, CKV, Vt, Cx, nullptr, 0, DDIM, 2 * DDIM);

        // 6) h2 = LN(h + cactx) -> h2 (Eb reuse)
        add_ln_kernel<<<dim3(M), dim3(256), 0, stream>>>(
            h, Cx, nullptr, n2_g, n2_b, h2, nullptr);

        // 7) MERGED vis | int: 256 + 512 = 768 blocks (3/CU).
        GemmOp ovis{};
        ovis.A = CQ;  ovis.lda = DDIM;     ovis.sA1 = SLD;               ovis.sA2 = 0;
        ovis.B = CKV; ovis.ldb = 2 * DDIM; ovis.sB1 = (long)LTOK * 2 * DDIM; ovis.sB2 = 0;
        ovis.C = nullptr; ovis.Cf = visp + (long)b0 * SSC;
        ovis.VTp = nullptr; ovis.vtcol0 = 0;
        ovis.ldc = LTOK; ovis.sC1 = SSC; ovis.sC2 = 0;
        ovis.M = LTOK; ovis.N = LTOK; ovis.K = DDIM; ovis.zdiv = 1;
        ovis.bias = nullptr; ovis.scale = 1.f / 128.f; ovis.flags = 0;
        ovis.nblk = (LTOK / 128) * (LTOK / 128) * cb;     // 16 * cb
        launch(ovis,
               mkop(h2, DDIM, Wint, DDIM, I, nullptr, DDIM,
                    M, DDIM, DDIM, int_b, 1.f, 1));

        // 8) G = inter @ out_w + out_b -> G (Cx reuse; LN2 consumed Cx)
        launch(mkop(I, DDIM, Wout, DDIM, G, nullptr, DDIM,
                    M, DDIM, DDIM, out_b, 1.f, 0), nil);

        // 9) out = LN(G + inter) -> fp32 d_out
        add_ln_kernel<<<dim3(M), dim3(256), 0, stream>>>(
            G, I, nullptr, out_g, out_bt, nullptr, outp + (long)b0 * SLD);
    }
}